// Round 7
// baseline (374.844 us; speedup 1.0000x reference)
//
#include <hip/hip_runtime.h>
#include <hip/hip_bf16.h>

// Problem constants
#define B_    4
#define D_    256
#define H_    56
#define W_    56
#define NH_   28
#define NW_   28
#define HEADS 8
#define DPH   32
#define NPOS  784      // 28*28
#define NS    3136     // 56*56

typedef unsigned short ushort_t;
typedef unsigned int uint_t;
typedef __attribute__((ext_vector_type(8))) short bf16x8;
typedef __attribute__((ext_vector_type(4))) float f32x4;

// ws layout (float offsets)
#define OFF_REC     0u          // packed u32 [4][512][784]      1,605,632
#define OFF_HPART   1605632u    // f32 [4cs][4b][784][256]       3,211,264
#define OFF_WREPC   4816896u    // conv wrep hi+lo (6,553,600 us) 3,276,800
#define OFF_LOC     8093696u    // f32 [32][784][2]              50,176
#define OFF_SAMP    8143872u    // f32 [32][32][784]             802,816
#define OFF_KTB     8946688u    // bf16 [32][784][32]            401,408
#define OFF_VTB     9348096u    // bf16 [32][32][784]+pad        401,472
#define OFF_W256    9749568u    // qw/ow hi+lo (262,144 us)      131,072
// aliases (lifetime-disjoint):
#define OFF_QPE     4816896u    // packed u32 [4][3136][256] (alias WREPC, dead after conv)
#define OFF_QBF     0u          // bf16 [4][3136][256] (alias REC, dead after conv)
#define OFF_ATTNT   1605632u    // packed u32 [4][3136][256] (alias HPART, dead after lnoff)
// total 9,880,640 floats = 39.5 MB

__device__ __forceinline__ ushort_t bf16rne(float f) {
    uint_t u = __float_as_uint(f);
    return (ushort_t)((u + 0x7FFFu + ((u >> 16) & 1u)) >> 16);
}
__device__ __forceinline__ float ubf(ushort_t h) {
    return __uint_as_float(((uint_t)h) << 16);
}
__device__ __forceinline__ uint_t packsplit(float v) {
    ushort_t hi = bf16rne(v);
    ushort_t lo = bf16rne(v - ubf(hi));
    return ((uint_t)hi << 16) | (uint_t)lo;
}
__device__ __forceinline__ uint_t cvtpk_bf16(float a, float b) {
    uint_t r;
    asm("v_cvt_pk_bf16_f32 %0, %1, %2" : "=v"(r) : "v"(a), "v"(b));
    return r;
}
__device__ __forceinline__ bf16x8 mk8(uint_t a, uint_t b, uint_t c, uint_t d) {
    union { uint_t u[4]; bf16x8 v; } x;
    x.u[0] = a; x.u[1] = b; x.u[2] = c; x.u[3] = d;
    return x.v;
}

// ---------------------------------------------------------------------------
// 1. 2x2 avg-pool of query|x -> rec packed-split u32 [4][512][784]
__global__ __launch_bounds__(256) void k_pool(const float* __restrict__ q,
                                              const float* __restrict__ x,
                                              uint_t* __restrict__ rec) {
    int idx = blockIdx.x * 256 + threadIdx.x;      // 1,605,632 exact
    int j = idx % NW_;
    int i = (idx / NW_) % NH_;
    int c = (idx / NPOS) % 512;
    int b = idx / (NPOS * 512);
    const float* src = (c < 256) ? q : x;
    int cc = (c < 256) ? c : (c - 256);
    const float* p = src + ((size_t)(b * 256 + cc) * H_ + i * 2) * W_ + j * 2;
    float v = 0.25f * (p[0] + p[1] + p[W_] + p[W_ + 1]);
    rec[idx] = packsplit(v);
}

// ---------------------------------------------------------------------------
// 1b. repack conv weights -> wrep_hi/lo[tap][oc][c] bf16 split.
__global__ __launch_bounds__(256) void k_wrepack(const float* __restrict__ w1,
                                                 ushort_t* __restrict__ wh,
                                                 ushort_t* __restrict__ wl) {
    int idx = blockIdx.x * 256 + threadIdx.x;  // 131072 = oc*512 + c
    const float* wp = w1 + (size_t)idx * 25;
    int oc = idx >> 9, c = idx & 511;
    #pragma unroll 5
    for (int tap = 0; tap < 25; ++tap) {
        float v = wp[tap];
        ushort_t h = bf16rne(v);
        ushort_t l = bf16rne(v - ubf(h));
        size_t o = ((size_t)tap * 256 + oc) * 512 + c;
        wh[o] = h;
        wl[o] = l;
    }
}

// 1c. repack q_w and o_w -> [oc][c] hi/lo
__global__ __launch_bounds__(256) void k_wrep256(const float* __restrict__ qw,
                                                 const float* __restrict__ ow,
                                                 ushort_t* __restrict__ w256) {
    int idx = blockIdx.x * 256 + threadIdx.x;   // 65536
    float qv = qw[idx], ov = ow[idx];
    ushort_t qh = bf16rne(qv);
    w256[idx] = qh;
    w256[idx + 65536] = bf16rne(qv - ubf(qh));
    ushort_t oh = bf16rne(ov);
    w256[idx + 131072] = oh;
    w256[idx + 196608] = bf16rne(ov - ubf(oh));
}

// ---------------------------------------------------------------------------
// 2. conv5x5 (512->256) as 25 shifted MFMA GEMMs, bf16 2-way split.
//    Grid 224 = 28u x 8ntcs (XCD-affine weight slices). 512 thr = 8 waves
//    = 4wm(32pos) x 2wn(64oc); wave = 2mf x 4nf -> per tap: 4 A-ds_reads,
//    8 B-global loads (prefetched), 24 MFMAs => MFMA:LDS ~2.4:1.
//    LDS pitch 32us + XOR slot swizzle; T14 async-stage for A.
__global__ __launch_bounds__(512) void k_conv_mfma(const uint_t* __restrict__ rec,
                                                   const ushort_t* __restrict__ wrep_hi,
                                                   float* __restrict__ hpart) {
    const int bid = blockIdx.x;
    const int ntcs = bid & 7;
    const int u = bid >> 3;              // 0..27
    const int mt = u % 7;
    const int b  = u / 7;
    const int nt = ntcs & 1;
    const int cs = ntcs >> 1;

    const int tid  = threadIdx.x;
    const int lane = tid & 63;
    const int wid  = tid >> 6;
    const int wm = wid & 3, wn = wid >> 2;    // 4 pos-groups x 2 oc-groups
    const int m_in = lane & 15, g = lane >> 4;

    const int p0  = mt * 128;
    const int ylo = p0 / 28;

    // sA: hi [320 plin][32 c] (XOR-swizzled 16B slots), lo at +10240
    __shared__ __align__(16) ushort_t sA[20480];

    int plinb[2];
    #pragma unroll
    for (int mf = 0; mf < 2; ++mf) {
        int p = p0 + wm * 32 + mf * 16 + m_in;
        int y = p / 28, xx = p - y * 28;
        plinb[mf] = (y - ylo) * 32 + xx;
    }

    const int oc0 = nt * 128 + wn * 64;
    const ushort_t* bp[4];
    #pragma unroll
    for (int nf = 0; nf < 4; ++nf)
        bp[nf] = wrep_hi + ((size_t)(oc0 + nf * 16 + m_in) << 9) + (g << 3);

    f32x4 acc[2][4];
    #pragma unroll
    for (int i = 0; i < 2; ++i)
        #pragma unroll
        for (int j = 0; j < 4; ++j)
            acc[i][j] = (f32x4){0.f, 0.f, 0.f, 0.f};

    // --- staging slot descriptors: slot it handles flat v = tid + 512*it,
    //     valid while v < 1280 (it<2 always; it==2 only for tid<256).
    int  s_pl[3], s_cg[3];
    bool s_ok[3];
    const uint_t* s_rp[3];
    #pragma unroll
    for (int it = 0; it < 3; ++it) {
        int v  = tid + it * 512;
        bool valid = (v < 1280);
        int cg = v & 3, pl = v >> 2;      // pl 0..319
        int ty = pl >> 5, tx = pl & 31;
        int yi = ylo - 2 + ty, xi = tx - 2;
        bool ok = valid && (yi >= 0) && (yi < 28) && (xi >= 0) && (xi < 28);
        s_pl[it] = pl; s_cg[it] = cg; s_ok[it] = ok;
        int off = ok ? (yi * 28 + xi) : 0;
        s_rp[it] = rec + ((size_t)(b * 512 + cg * 8)) * NPOS + off;
    }
    uint_t st[3][8];

#define STAGE_LOAD(CB) do {                                                  \
    _Pragma("unroll")                                                        \
    for (int it_ = 0; it_ < 3; ++it_) {                                      \
        if (it_ < 2 || tid < 256) {                                          \
            const uint_t* rp_ = s_rp[it_] + (size_t)(CB) * NPOS;             \
            _Pragma("unroll")                                                \
            for (int i_ = 0; i_ < 8; ++i_)                                   \
                st[it_][i_] = s_ok[it_] ? rp_[(size_t)i_ * NPOS] : 0u;       \
        } } } while (0)

#define STAGE_WRITE() do {                                                   \
    _Pragma("unroll")                                                        \
    for (int it_ = 0; it_ < 3; ++it_) {                                      \
        if (it_ < 2 || tid < 256) {                                          \
            uint_t hw_[4], lw_[4];                                           \
            _Pragma("unroll")                                                \
            for (int j_ = 0; j_ < 4; ++j_) {                                 \
                hw_[j_] = (st[it_][2*j_] >> 16) | (st[it_][2*j_+1] & 0xFFFF0000u); \
                lw_[j_] = (st[it_][2*j_] & 0xFFFFu) | (st[it_][2*j_+1] << 16);     \
            }                                                                \
            int pl_ = s_pl[it_];                                             \
            int cw_ = s_cg[it_] ^ ((pl_ >> 1) & 3);                          \
            *(uint4*)(sA + pl_ * 32 + cw_ * 8) =                             \
                make_uint4(hw_[0], hw_[1], hw_[2], hw_[3]);                  \
            *(uint4*)(sA + 10240 + pl_ * 32 + cw_ * 8) =                     \
                make_uint4(lw_[0], lw_[1], lw_[2], lw_[3]);                  \
        } } } while (0)

#define LOADB(BH, BL, TAP, CB) do {                                          \
    size_t tof_ = (size_t)(TAP) * 131072 + (CB);                             \
    _Pragma("unroll")                                                        \
    for (int nf_ = 0; nf_ < 4; ++nf_) {                                      \
        BH[nf_] = *(const bf16x8*)(bp[nf_] + tof_);                          \
        BL[nf_] = *(const bf16x8*)(bp[nf_] + tof_ + 3276800u);               \
    } } while (0)

#define TAPBODY(BH, BL, TOFF) do {                                           \
    int to_ = (TOFF);                                                        \
    _Pragma("unroll")                                                        \
    for (int mf_ = 0; mf_ < 2; ++mf_) {                                      \
        const int pl_ = plinb[mf_] + to_;                                    \
        const int ao_ = (pl_ << 5) + ((g ^ ((pl_ >> 1) & 3)) << 3);          \
        bf16x8 ah_ = *(const bf16x8*)(sA + ao_);                             \
        bf16x8 al_ = *(const bf16x8*)(sA + 10240 + ao_);                     \
        _Pragma("unroll")                                                    \
        for (int nf_ = 0; nf_ < 4; ++nf_) {                                  \
            acc[mf_][nf_] = __builtin_amdgcn_mfma_f32_16x16x32_bf16(         \
                ah_, BH[nf_], acc[mf_][nf_], 0, 0, 0);                       \
            acc[mf_][nf_] = __builtin_amdgcn_mfma_f32_16x16x32_bf16(         \
                ah_, BL[nf_], acc[mf_][nf_], 0, 0, 0);                       \
            acc[mf_][nf_] = __builtin_amdgcn_mfma_f32_16x16x32_bf16(         \
                al_, BH[nf_], acc[mf_][nf_], 0, 0, 0);                       \
        } } } while (0)

    STAGE_LOAD(cs * 128);                 // chunk 0 loads in flight

    for (int ch = 0; ch < 4; ++ch) {
        const int cb = cs * 128 + ch * 32;

        __syncthreads();                  // buffer free (prev chunk reads done)
        STAGE_WRITE();                    // ds_write chunk ch (loads returned)
        __syncthreads();                  // buffer ready
        if (ch < 3) STAGE_LOAD(cb + 32);  // issue next chunk loads early (T14)

        bf16x8 bh0[4], bl0[4], bh1[4], bl1[4];
        LOADB(bh0, bl0, 0, cb);
        for (int t = 0; t < 24; t += 2) {
            int t1 = t + 1, t2 = (t + 2 <= 24) ? t + 2 : 24;
            LOADB(bh1, bl1, t1, cb);
            TAPBODY(bh0, bl0, (t / 5) * 32 + (t % 5));
            LOADB(bh0, bl0, t2, cb);
            TAPBODY(bh1, bl1, (t1 / 5) * 32 + (t1 % 5));
        }
        TAPBODY(bh0, bl0, 4 * 32 + 4);
    }

    #pragma unroll
    for (int mf = 0; mf < 2; ++mf) {
        int prow = p0 + wm * 32 + mf * 16 + g * 4;
        #pragma unroll
        for (int nf = 0; nf < 4; ++nf) {
            int oc = oc0 + nf * 16 + m_in;
            #pragma unroll
            for (int r = 0; r < 4; ++r) {
                int pos = prow + r;
                if (pos < NPOS)
                    hpart[(((size_t)(cs * 4 + b) * NPOS + pos) << 8) + oc] =
                        acc[mf][nf][r];
            }
        }
    }
#undef STAGE_LOAD
#undef STAGE_WRITE
#undef LOADB
#undef TAPBODY
}

// ---------------------------------------------------------------------------
// 3. reduce partials + bias + channel-LN + GELU + 1x1(256->16) + tanh + clip
__global__ __launch_bounds__(256) void k_lnoff(const float* __restrict__ hpart,
                                               const float* __restrict__ b1,
                                               const float* __restrict__ g,
                                               const float* __restrict__ bb,
                                               const float* __restrict__ w2,
                                               const float* __restrict__ b2,
                                               const float* __restrict__ ref,
                                               float* __restrict__ loc) {
    const int pos = blockIdx.x, b = blockIdx.y, c = threadIdx.x;
    float v = b1[c];
    #pragma unroll
    for (int cs = 0; cs < 4; ++cs)
        v += hpart[((size_t)((cs * 4 + b) * NPOS + pos)) * 256 + c];

    float s1 = v, s2 = v * v;
    #pragma unroll
    for (int m = 32; m >= 1; m >>= 1) {
        s1 += __shfl_xor(s1, m);
        s2 += __shfl_xor(s2, m);
    }
    __shared__ float r1[4], r2[4];
    const int wv = c >> 6, ln = c & 63;
    if (ln == 0) { r1[wv] = s1; r2[wv] = s2; }
    __syncthreads();
    s1 = r1[0] + r1[1] + r1[2] + r1[3];
    s2 = r2[0] + r2[1] + r2[2] + r2[3];
    const float mu  = s1 * (1.f / 256.f);
    const float var = s2 * (1.f / 256.f) - mu * mu;
    const float rstd = 1.f / sqrtf(var + 1e-5f);
    const float xn = (v - mu) * rstd * g[c] + bb[c];
    const float ge = 0.5f * xn * (1.f + erff(xn * 0.70710678118654752f));

    __shared__ float ro[4][16];
    for (int o = 0; o < 16; ++o) {
        float pv = ge * w2[o * 256 + c];
        #pragma unroll
        for (int m = 32; m >= 1; m >>= 1) pv += __shfl_xor(pv, m);
        if (ln == 0) ro[wv][o] = pv;
    }
    __syncthreads();
    if (c < 16) {
        float off = ro[0][c] + ro[1][c] + ro[2][c] + ro[3][c] + b2[c];
        float t = tanhf(off);
        int hd = c >> 1, comp = c & 1;
        size_t li = ((size_t)((b * 8 + hd) * NPOS + pos)) * 2 + comp;
        float l = ref[li] + t;
        loc[li] = fminf(1.f, fmaxf(-1.f, l));
    }
}

// ---------------------------------------------------------------------------
// 4. bilinear grid_sample, zeros padding -> samp[32][32][784].
__global__ __launch_bounds__(256) void k_gsample(const float* __restrict__ x,
                                                 const float* __restrict__ loc,
                                                 float* __restrict__ samp) {
    int idx = blockIdx.x * 256 + threadIdx.x;      // 25,088 exact
    int pos = idx % NPOS;
    int bh  = idx / NPOS;
    float gx = loc[(size_t)idx * 2 + 0];
    float gy = loc[(size_t)idx * 2 + 1];
    float ix = (gx + 1.f) * 28.f - 0.5f;
    float iy = (gy + 1.f) * 28.f - 0.5f;
    float x0f = floorf(ix), y0f = floorf(iy);
    int x0 = (int)x0f, y0 = (int)y0f;
    float wx = ix - x0f, wy = iy - y0f;

    int xs[2] = { x0, x0 + 1 };
    int ys[2] = { y0, y0 + 1 };
    float wxs[2] = { 1.f - wx, wx };
    float wys[2] = { 1.f - wy, wy };
    int   cidx[4];
    float cw[4];
    #pragma unroll
    for (int a = 0; a < 2; ++a)
        #pragma unroll
        for (int bb2 = 0; bb2 < 2; ++bb2) {
            int yy = ys[a], xx = xs[bb2];
            bool inb = (xx >= 0) && (xx < W_) && (yy >= 0) && (yy < H_);
            int yyc = min(max(yy, 0), H_ - 1), xxc = min(max(xx, 0), W_ - 1);
            cidx[a * 2 + bb2] = yyc * W_ + xxc;
            cw[a * 2 + bb2] = inb ? (wys[a] * wxs[bb2]) : 0.f;
        }

    const float* xb = x + (size_t)bh * DPH * NS;
    #pragma unroll 4
    for (int c = 0; c < DPH; ++c) {
        const float* xc = xb + (size_t)c * NS;
        float v = cw[0] * xc[cidx[0]] + cw[1] * xc[cidx[1]]
                + cw[2] * xc[cidx[2]] + cw[3] * xc[cidx[3]];
        samp[((size_t)bh * DPH + c) * NPOS + pos] = v;
    }
}

// ---------------------------------------------------------------------------
// 4b. qpe = (query + pos_emb) transposed to [b][s][256] packed-split u32.
__global__ __launch_bounds__(256) void k_qpe(const float* __restrict__ q,
                                             const float* __restrict__ pe,
                                             uint_t* __restrict__ qpe) {
    const int st = blockIdx.x, b = blockIdx.y;
    const int s0 = st * 64;
    __shared__ uint_t T[64 * 129];
    const int l = threadIdx.x & 63, w = threadIdx.x >> 6;

    for (int half = 0; half < 2; ++half) {
        #pragma unroll 4
        for (int cc = 0; cc < 32; ++cc) {
            int c = half * 128 + w * 32 + cc;
            size_t gi = (size_t)(b * 256 + c) * NS + s0 + l;
            T[l * 129 + w * 32 + cc] = packsplit(q[gi] + pe[gi]);
        }
        __syncthreads();
        {
            int s = threadIdx.x >> 2, q4 = threadIdx.x & 3;
            uint_t* dst = qpe + ((size_t)b * NS + s0 + s) * 256 + half * 128 + q4 * 32;
            const uint_t* src = T + s * 129 + q4 * 32;
            #pragma unroll
            for (int i = 0; i < 8; ++i) {
                uint_t a0 = src[i * 4], a1 = src[i * 4 + 1];
                uint_t a2 = src[i * 4 + 2], a3 = src[i * 4 + 3];
                *(uint4*)(dst + i * 4) = make_uint4(a0, a1, a2, a3);
            }
        }
        __syncthreads();
    }
}

// ---------------------------------------------------------------------------
// 5. streaming MFMA 256x256 projection, wave = 2mf x 2nf (32oc x 32s).
//    grid (49, 4, 4) = 784 blocks, 3136 waves. NS = 49*64 exact -> no guards.
//    MODE 0: out bf16 [b][s][256] (+bias); MODE 1: out f32 [b][256][3136].
template<int MODE>
__global__ __launch_bounds__(256) void k_proj(const uint_t* __restrict__ inT,
                                              const ushort_t* __restrict__ wh,
                                              const ushort_t* __restrict__ wl,
                                              const float* __restrict__ bias,
                                              float* __restrict__ outf,
                                              ushort_t* __restrict__ outb) {
    const int st = blockIdx.x, og = blockIdx.y, b = blockIdx.z;
    const int tid = threadIdx.x, lane = tid & 63, wid = tid >> 6;
    const int wsg = wid & 1, wo = wid >> 1;
    const int n = lane & 15, g = lane >> 4;
    const int s0 = st * 64 + wsg * 32;
    const int oc0 = og * 64 + wo * 32;
    const uint_t* ibase = inT + (size_t)b * NS * 256;

    f32x4 acc[2][2];
    #pragma unroll
    for (int i = 0; i < 2; ++i)
        #pragma unroll
        for (int j = 0; j < 2; ++j)
            acc[i][j] = (f32x4){0.f, 0.f, 0.f, 0.f};

    #pragma unroll 2
    for (int kf = 0; kf < 8; ++kf) {
        const int ko = kf * 32 + g * 8;
        bf16x8 awh[2], awl[2];
        #pragma unroll
        for (int mf = 0; mf < 2; ++mf) {
            size_t a = (size_t)(oc0 + mf * 16 + n) * 256 + ko;
            awh[mf] = *(const bf16x8*)(wh + a);
            awl[mf] = *(const bf16x8*)(wl + a);
        }
        bf16x8 bh[2], bl[2];
        #pragma unroll
        for (int nf = 0; nf < 2; ++nf) {
            const uint4* p = (const uint4*)(ibase + (size_t)(s0 + nf * 16 + n) * 256 + ko);
            uint4 u = p[0], v = p[1];
            bh[nf] = mk8((u.x >> 16) | (u.y & 0xFFFF0000u),
                         (u.z >> 16) | (u.w & 0xFFFF0000u),
                         (v.x >> 16) | (v.y & 0xFFFF0000u),
                         (v.z >> 16) | (v.w & 0xFFFF0000u));
            bl[nf] = mk8((u.x & 0xFFFFu) | (u.y << 16),
                         (u.z & 0xFFFFu) | (u.w << 16),
                         (v.x & 0xFFFFu) | (v.y << 16),
                         (v.z & 0xFFFFu) | (v.w << 16));
        }
        #pragma unroll
        for (int mf = 0; mf < 2; ++mf)
            #pragma unroll
            for (int nf = 0; nf < 2; ++nf) {
                acc[mf][nf] = __builtin_amdgcn_mfma_f32_16x16x32_bf16(
                    awh[mf], bh[nf], acc[mf][nf], 0, 0, 0);
                acc[mf][nf] = __builtin_amdgcn_mfma_f32_16x16x32_bf16(
                    awh[mf], bl[nf], acc[mf][nf], 0, 0, 0);
                acc[mf][nf] = __builtin_amdgcn_mfma_f32_16x16x32_bf16(
                    awl[mf], bh[nf], acc[mf][nf], 0, 0, 0);
            }
    }

    #pragma unroll
    for (int mf = 0; mf < 2; ++mf) {
        const int ocr = oc0 + mf * 16 + g * 4;
        float bs[4];
        #pragma unroll
        for (int r = 0; r < 4; ++r) bs[r] = bias[ocr + r];
        #pragma unroll
        for (int nf = 0; nf < 2; ++nf) {
            int sc = s0 + nf * 16 + n;
            if (MODE == 0) {
                uint_t p0 = (uint_t)bf16rne(acc[mf][nf][0] + bs[0])
                          | ((uint_t)bf16rne(acc[mf][nf][1] + bs[1]) << 16);
                uint_t p1 = (uint_t)bf16rne(acc[mf][nf][2] + bs[2])
                          | ((uint_t)bf16rne(acc[mf][nf][3] + bs[3]) << 16);
                *(uint2*)(outb + ((size_t)b * NS + sc) * 256 + ocr) =
                    make_uint2(p0, p1);
            } else {
                #pragma unroll
                for (int r = 0; r < 4; ++r)
                    outf[(size_t)(b * 256 + ocr + r) * NS + sc] =
                        acc[mf][nf][r] + bs[r];
            }
        }
    }
}

// ---------------------------------------------------------------------------
// 6. k/v 32->32 projections -> bf16: ktb[bh][pos][32], vtb[bh][dph][pos].
__global__ __launch_bounds__(256) void k_kv(const float* __restrict__ samp,
                                            const float* __restrict__ kw,
                                            const float* __restrict__ kb,
                                            const float* __restrict__ vw,
                                            const float* __restrict__ vb,
                                            ushort_t* __restrict__ ktb,
                                            ushort_t* __restrict__ vtb) {
    __shared__ __align__(16) float kl[1024], vl[1024];
    const int tid = threadIdx.x;
    for (int i = tid; i < 1024; i += 256) {
        int o = i >> 5, c = i & 31;
        kl[c * 32 + o] = kw[i];
        vl[c * 32 + o] = vw[i];
    }
    __syncthreads();
    int idx = blockIdx.x * 256 + tid;   // 25,088 exact
    int pos = idx % NPOS;
    int bh  = idx / NPOS;
    const float* sp = samp + (size_t)bh * DPH * NPOS + pos;
    float ak[32] = {}, av[32] = {};
    for (int c = 0; c < 32; ++c) {
        float sv = sp[(size_t)c * NPOS];
        #pragma unroll
        for (int og = 0; og < 8; ++og) {
            float4 k4 = *(const float4*)&kl[c * 32 + og * 4];
            float4 v4 = *(const float4*)&vl[c * 32 + og * 4];
            ak[og * 4 + 0] = fmaf(sv, k4.x, ak[og * 4 + 0]);
            ak[og * 4 + 1] = fmaf(sv, k4.y, ak[og * 4 + 1]);
            ak[og * 4 + 2] = fmaf(sv, k4.z, ak[og * 4 + 2]);
            ak[og * 4 + 3] = fmaf(sv, k4.w, ak[og * 4 + 3]);
            av[og * 4 + 0] = fmaf(sv, v4.x, av[og * 4 + 0]);
            av[og * 4 + 1] = fmaf(sv, v4.y, av[og * 4 + 1]);
            av[og * 4 + 2] = fmaf(sv, v4.z, av[og * 4 + 2]);
            av[og * 4 + 3] = fmaf(sv, v4.w, av[og * 4 + 3]);
        }
    }
    uint_t kp[16];
    #pragma unroll
    for (int o = 0; o < 16; ++o)
        kp[o] = (uint_t)bf16rne(ak[2 * o] + kb[2 * o])
              | ((uint_t)bf16rne(ak[2 * o + 1] + kb[2 * o + 1]) << 16);
    uint4* kdst = (uint4*)(ktb + (size_t)idx * 32);
    kdst[0] = make_uint4(kp[0], kp[1], kp[2], kp[3]);
    kdst[1] = make_uint4(kp[4], kp[5], kp[6], kp[7]);
    kdst[2] = make_uint4(kp[8], kp[9], kp[10], kp[11]);
    kdst[3] = make_uint4(kp[12], kp[13], kp[14], kp[15]);
    #pragma unroll
    for (int o = 0; o < 32; ++o)
        vtb[((size_t)bh * 32 + o) * NPOS + pos] = bf16rne(av[o] + vb[o]);
}

// ---------------------------------------------------------------------------
// 7. MFMA flash attention. grid (25 qtile, 32 bh), 256 thr = 4 waves.
//    Wave = 32 q rows (2 nf frags); K/V frags direct from global; no barriers.
__global__ __launch_bounds__(256) void k_attn_mfma(const ushort_t* __restrict__ qbf,
                                                   const ushort_t* __restrict__ ktb,
                                                   const ushort_t* __restrict__ vtb,
                                                   uint_t* __restrict__ attnT) {
    const int qt = blockIdx.x, bh = blockIdx.y;
    const int b = bh >> 3, head = bh & 7;
    const int tid = threadIdx.x, lane = tid & 63, wid = tid >> 6;
    const int n = lane & 15, g = lane >> 4;

    __shared__ __align__(16) ushort_t sP[4][32 * 72];    // per-wave [q][kv], pad 72

    const int q0 = qt * 128 + wid * 32;

    bf16x8 qf[2];
    #pragma unroll
    for (int nf = 0; nf < 2; ++nf) {
        int srow = min(q0 + nf * 16 + n, NS - 1);
        qf[nf] = *(const bf16x8*)(qbf + ((size_t)b * NS + srow) * 256 + head * 32 + g * 8);
    }

    const ushort_t* kbase = ktb + (size_t)bh * NPOS * 32;
    const ushort_t* vbase = vtb + (size_t)bh * 32 * NPOS;
    ushort_t* myP = sP[wid];

    f32x4 o_acc[2][2];
    #pragma unroll
    for (int i = 0; i < 2; ++i)
        #pragma unroll
        for (int j = 0; j < 2; ++j)
            o_acc[i][j] = (f32x4){0.f, 0.f, 0.f, 0.f};
    float mrun[2] = {-1e30f, -1e30f};
    float lrun[2] = {0.f, 0.f};

    for (int t = 0; t < 12; ++t) {
        const int kvt = t * 64;
        bf16x8 kf[4];
        #pragma unroll
        for (int mf = 0; mf < 4; ++mf)
            kf[mf] = *(const bf16x8*)(kbase + (size_t)(kvt + mf * 16 + n) * 32 + g * 8);
        bf16x8 vf[2][2];
        #pragma unroll
        for (int mv = 0; mv < 2; ++mv)
            #pragma unroll
            for (int kc = 0; kc < 2; ++kc)
                vf[mv][kc] = *(const bf16x8*)(vbase + (size_t)(mv * 16 + n) * NPOS
                                              + kvt + kc * 32 + g * 8);

        f32x4 acc[4][2];
        #pragma unroll
        for (int mf = 0; mf < 4; ++mf)
            #pragma unroll
            for (int nf = 0; nf < 2; ++nf)
                acc[mf][nf] = __builtin_amdgcn_mfma_f32_16x16x32_bf16(
                    kf[mf], qf[nf], (f32x4){0.f, 0.f, 0.f, 0.f}, 0, 0, 0);

        #pragma unroll
        for (int nf = 0; nf < 2; ++nf) {
            float s[4][4];
            float tmax = -1e30f;
            #pragma unroll
            for (int mf = 0; mf < 4; ++mf)
                #pragma unroll
                for (int r = 0; r < 4; ++r) {
                    s[mf][r] = acc[mf][nf][r] * (1.f / 16.f);
                    tmax = fmaxf(tmax, s[mf][r]);
                }
            tmax = fmaxf(tmax, __shfl_xor(tmax, 16));
            tmax = fmaxf(tmax, __shfl_xor(tmax, 32));
            float mnew = fmaxf(mrun[nf], tmax);
            float corr = __expf(mrun[nf] - mnew);
            mrun[nf] = mnew;
            float psum = 0.f;
            float p[4][4];
            #pragma unroll
            for (int mf = 0; mf < 4; ++mf)
                #pragma unroll
                for (int r = 0; r < 4; ++r) {
                    p[mf][r] = __expf(s[mf][r] - mnew);
                    psum += p[mf][r];
                }
            psum += __shfl_xor(psum, 16);
            psum += __shfl_xor(psum, 32);
            lrun[nf] = lrun[nf] * corr + psum;
            #pragma unroll
            for (int mv = 0; mv < 2; ++mv)
                #pragma unroll
                for (int r = 0; r < 4; ++r)
                    o_acc[mv][nf][r] *= corr;
            #pragma unroll
            for (int mf = 0; mf < 4; ++mf) {
                uint_t lo = cvtpk_bf16(p[mf][0], p[mf][1]);
                uint_t hi = cvtpk_bf16(p[mf][2], p[mf][3]);
                *(uint2*)(myP + (nf * 16 + n) * 72 + mf * 16 + g * 4) =
                    make_uint2(lo, hi);
            }
        }

        #pragma unroll
        for (int kc = 0; kc < 2; ++kc)
            #pragma unroll
            for (int nf = 0; nf < 2; ++nf) {
                bf16x8 pb = *(const bf16x8*)(myP + (nf * 16 + n) * 72
                                             + kc * 32 + g * 8);
                #pragma unroll
                for (int mv = 0; mv < 2; ++mv)
                    o_acc[mv][nf] = __builtin_amdgcn_mfma_f32_16x16x32_bf16(
                        vf[mv][kc], pb, o_acc[mv][nf], 0, 0, 0);
            }
    }

    // epilog tile: kv 768..783
    {
        const int kvt = 768;
        bf16x8 kf0 = *(const bf16x8*)(kbase + (size_t)(kvt + n) * 32 + g * 8);
        bf16x8 vf[2];
        int kvo = kvt + g * 8; if (kvo > 776) kvo = 776;
        #pragma unroll
        for (int mv = 0; mv < 2; ++mv)
            vf[mv] = *(const bf16x8*)(vbase + (size_t)(mv * 16 + n) * NPOS + kvo);

        f32x4 acc0[2];
        #pragma unroll
        for (int nf = 0; nf < 2; ++nf)
            acc0[nf] = __builtin_amdgcn_mfma_f32_16x16x32_bf16(
                kf0, qf[nf], (f32x4){0.f, 0.f, 0.f, 0.f}, 0, 0, 0);

        #pragma unroll
        for (int nf = 0; nf < 2; ++nf) {
            float s[4], tmax = -1e30f;
            #pragma unroll
            for (int r = 0; r < 4; ++r) {
                s[r] = acc0[nf][r] * (1.f / 16.f);
                tmax = fmaxf(tmax, s[r]);
            }
            tmax = fmaxf(tmax, __shfl_xor(tmax, 16));
            tmax = fmaxf(tmax, __shfl_xor(tmax, 32));
            float mnew = fmaxf(mrun[nf], tmax);
            float corr = __expf(mrun[nf] - mnew);
            mrun[nf] = mnew;
            float psum = 0.f, p[4];
            #pragma unroll
            for (int r = 0; r < 4; ++r) { p[r] = __expf(s[r] - mnew); psum += p[r]; }
            psum += __shfl_xor(psum, 16);
            psum += __shfl_xor(psum, 32);
            lrun[nf] = lrun[nf] * corr + psum;
            #pragma unroll
            for (int mv = 0; mv < 2; ++mv)
                #pragma unroll
                for (int r = 0; r < 4; ++r)
                    o_acc[mv][nf][r] *= corr;
            uint_t lo = cvtpk_bf16(p[0], p[1]);
            uint_t hi = cvtpk_bf16(p[2], p[3]);
            *(uint2*)(myP + (nf * 16 + n) * 72 + g * 4) = make_uint2(lo, hi);
            *(uint2*)(myP + (nf * 16 + n) * 72 + 16 + g * 4) = make_uint2(0u, 0u);
        }
        #pragma unroll
        for (int nf = 0; nf < 2; ++nf) {
            bf16x8 pb = *(const bf16x8*)(myP + (nf * 16 + n) * 72 + g * 8);
            #pragma unroll
            for (int mv = 0; mv < 2; ++mv)
                o_acc[mv][nf] = __builtin_amdgcn_mfma_f32_16x16x32_bf16(
                    vf[mv], pb, o_acc[mv][nf], 0, 0, 0);
        }
    }

    // normalize + store attnT packed-split [b][s][256]
    #pragma unroll
    for (int nf = 0; nf < 2; ++nf) {
        float inv = 1.f / lrun[nf];
        int qpos = q0 + nf * 16 + n;
        if (qpos < NS) {
            #pragma unroll
            for (int mv = 0; mv < 2; ++mv) {
                uint_t pk[4];
                #pragma unroll
                for (int r = 0; r < 4; ++r)
                    pk[r] = packsplit(o_acc[mv][nf][r] * inv);
                *(uint4*)(attnT + ((size_t)b * NS + qpos) * 256
                          + head * 32 + mv * 16 + g * 4) =
                    make_uint4(pk[0], pk[1], pk[2], pk[3]);
            }
        }
    }
}

// ---------------------------------------------------------------------------
extern "C" void kernel_launch(void* const* d_in, const int* in_sizes, int n_in,
                              void* d_out, int out_size, void* d_ws, size_t ws_size,
                              hipStream_t stream) {
    const float* query = (const float*)d_in[0];
    const float* x     = (const float*)d_in[1];
    const float* refp  = (const float*)d_in[2];
    const float* pe    = (const float*)d_in[3];
    const float* w1    = (const float*)d_in[4];
    const float* b1    = (const float*)d_in[5];
    const float* lng   = (const float*)d_in[6];
    const float* lnb   = (const float*)d_in[7];
    const float* w2    = (const float*)d_in[8];
    const float* b2    = (const float*)d_in[9];
    const float* qw    = (const float*)d_in[10];
    const float* qb    = (const float*)d_in[11];
    const float* kw    = (const float*)d_in[12];
    const float* kb    = (const float*)d_in[13];
    const float* vw    = (const float*)d_in[14];
    const float* vb    = (const float*)d_in[15];
    const float* ow    = (const float*)d_in[16];
    const float* ob    = (const float*)d_in[17];

    float* ws  = (float*)d_ws;
    float* out = (float*)d_out;

    uint_t*   rec    = (uint_t*)(ws + OFF_REC);
    float*    hpart  = ws + OFF_HPART;
    float*    loc    = ws + OFF_LOC;
    float*    samp   = ws + OFF_SAMP;
    ushort_t* ktb    = (ushort_t*)(ws + OFF_KTB);
    ushort_t* vtb    = (ushort_t*)(ws + OFF_VTB);
    ushort_t* w256   = (ushort_t*)(ws + OFF_W256);
    ushort_t* wrep_hi = (ushort_t*)(ws + OFF_WREPC);
    uint_t*   qpe    = (uint_t*)(ws + OFF_QPE);     // alias WREPC (dead after conv)
    ushort_t* qbf    = (ushort_t*)(ws + OFF_QBF);   // alias REC (dead after conv)
    uint_t*   attnT  = (uint_t*)(ws + OFF_ATTNT);   // alias HPART (dead after lnoff)

    ushort_t* qwh = w256;
    ushort_t* qwl = w256 + 65536;
    ushort_t* owh = w256 + 131072;
    ushort_t* owl = w256 + 196608;

    k_pool<<<6272, 256, 0, stream>>>(query, x, rec);
    k_wrepack<<<512, 256, 0, stream>>>(w1, wrep_hi, wrep_hi + 3276800u);
    k_wrep256<<<256, 256, 0, stream>>>(qw, ow, w256);
    k_conv_mfma<<<224, 512, 0, stream>>>(rec, wrep_hi, hpart);
    k_lnoff<<<dim3(784, 4), 256, 0, stream>>>(hpart, b1, lng, lnb, w2, b2, refp, loc);
    k_gsample<<<98, 256, 0, stream>>>(x, loc, samp);
    k_qpe<<<dim3(49, 4), 256, 0, stream>>>(query, pe, qpe);
    k_proj<0><<<dim3(49, 4, 4), 256, 0, stream>>>(qpe, qwh, qwl, qb, nullptr, qbf);
    k_kv<<<98, 256, 0, stream>>>(samp, kw, kb, vw, vb, ktb, vtb);
    k_attn_mfma<<<dim3(25, 32), 256, 0, stream>>>(qbf, ktb, vtb, attnT);
    k_proj<1><<<dim3(49, 4, 4), 256, 0, stream>>>(attnT, owh, owl, ob, out, nullptr);
}

// Round 8
// 254.878 us; speedup vs baseline: 1.4707x; 1.4707x over previous
//
#include <hip/hip_runtime.h>
#include <hip/hip_bf16.h>

// Problem constants
#define B_    4
#define D_    256
#define H_    56
#define W_    56
#define NH_   28
#define NW_   28
#define HEADS 8
#define DPH   32
#define NPOS  784      // 28*28
#define NS    3136     // 56*56

typedef unsigned short ushort_t;
typedef unsigned int uint_t;
typedef __attribute__((ext_vector_type(8))) short bf16x8;
typedef __attribute__((ext_vector_type(4))) float f32x4;

// ws layout (float offsets)
#define OFF_REC     0u          // packed u32 [4][512][784]      1,605,632
#define OFF_HPART   1605632u    // f32 [4cs][4b][784][256]       3,211,264
#define OFF_WREPC   4816896u    // conv wrep hi+lo (6,553,600 us) 3,276,800
#define OFF_LOC     8093696u    // f32 [32][784][2]              50,176
#define OFF_SAMP    8143872u    // f32 [32][32][784]             802,816
#define OFF_KTB     8946688u    // bf16 [32][784][32]            401,408
#define OFF_VTB     9348096u    // bf16 [32][32][784]+pad        401,472
#define OFF_W256    9749568u    // qw/ow hi+lo (262,144 us)      131,072
// aliases (lifetime-disjoint):
#define OFF_QPE     4816896u    // packed u32 [4][3136][256] (alias WREPC, dead after conv)
#define OFF_QBF     0u          // bf16 [4][3136][256] (alias REC, dead after conv)
#define OFF_ATTNT   1605632u    // packed u32 [4][3136][256] (alias HPART, dead after lnoff)
// total 9,880,640 floats = 39.5 MB

__device__ __forceinline__ ushort_t bf16rne(float f) {
    uint_t u = __float_as_uint(f);
    return (ushort_t)((u + 0x7FFFu + ((u >> 16) & 1u)) >> 16);
}
__device__ __forceinline__ float ubf(ushort_t h) {
    return __uint_as_float(((uint_t)h) << 16);
}
__device__ __forceinline__ uint_t packsplit(float v) {
    ushort_t hi = bf16rne(v);
    ushort_t lo = bf16rne(v - ubf(hi));
    return ((uint_t)hi << 16) | (uint_t)lo;
}
__device__ __forceinline__ uint_t cvtpk_bf16(float a, float b) {
    uint_t r;
    asm("v_cvt_pk_bf16_f32 %0, %1, %2" : "=v"(r) : "v"(a), "v"(b));
    return r;
}
__device__ __forceinline__ bf16x8 mk8(uint_t a, uint_t b, uint_t c, uint_t d) {
    union { uint_t u[4]; bf16x8 v; } x;
    x.u[0] = a; x.u[1] = b; x.u[2] = c; x.u[3] = d;
    return x.v;
}

// ---------------------------------------------------------------------------
// 1. 2x2 avg-pool of query|x -> rec packed-split u32 [4][512][784]
__global__ __launch_bounds__(256) void k_pool(const float* __restrict__ q,
                                              const float* __restrict__ x,
                                              uint_t* __restrict__ rec) {
    int idx = blockIdx.x * 256 + threadIdx.x;      // 1,605,632 exact
    int j = idx % NW_;
    int i = (idx / NW_) % NH_;
    int c = (idx / NPOS) % 512;
    int b = idx / (NPOS * 512);
    const float* src = (c < 256) ? q : x;
    int cc = (c < 256) ? c : (c - 256);
    const float* p = src + ((size_t)(b * 256 + cc) * H_ + i * 2) * W_ + j * 2;
    float v = 0.25f * (p[0] + p[1] + p[W_] + p[W_ + 1]);
    rec[idx] = packsplit(v);
}

// ---------------------------------------------------------------------------
// 1b. repack conv weights FRAGMENT-MAJOR:
//     wrep[tap][ocf(16)][cbi(16)][lane(64)][8] bf16 hi (lo at +3,276,800).
//     lane = g*16 + m_in holds w[oc=ocf*16+m_in][c=cbi*32+g*8 .. +7][tap].
//     A wave's B-frag load = 64 lanes x 16B = 1KB CONTIGUOUS (coalesced).
__global__ __launch_bounds__(256) void k_wrepack(const float* __restrict__ w1,
                                                 ushort_t* __restrict__ wh,
                                                 ushort_t* __restrict__ wl) {
    int idx = blockIdx.x * 256 + threadIdx.x;   // 409,600 = tap*16384+ocf*1024+cbi*64+lane
    int lane = idx & 63;
    int cbi  = (idx >> 6) & 15;
    int ocf  = (idx >> 10) & 15;
    int tap  = idx >> 14;                        // 0..24
    int m_in = lane & 15, g = lane >> 4;
    int oc = ocf * 16 + m_in;
    int c0 = cbi * 32 + g * 8;
    const float* wp = w1 + ((size_t)oc * 512 + c0) * 25 + tap;
    uint_t hp[4], lp[4];
    #pragma unroll
    for (int j = 0; j < 4; ++j) {
        float v0 = wp[(size_t)(2 * j) * 25];
        float v1 = wp[(size_t)(2 * j + 1) * 25];
        ushort_t h0 = bf16rne(v0), h1 = bf16rne(v1);
        ushort_t l0 = bf16rne(v0 - ubf(h0)), l1 = bf16rne(v1 - ubf(h1));
        hp[j] = (uint_t)h0 | ((uint_t)h1 << 16);
        lp[j] = (uint_t)l0 | ((uint_t)l1 << 16);
    }
    *(uint4*)(wh + (size_t)idx * 8) = make_uint4(hp[0], hp[1], hp[2], hp[3]);
    *(uint4*)(wl + (size_t)idx * 8) = make_uint4(lp[0], lp[1], lp[2], lp[3]);
}

// 1c. repack q_w and o_w -> [oc][c] hi/lo
__global__ __launch_bounds__(256) void k_wrep256(const float* __restrict__ qw,
                                                 const float* __restrict__ ow,
                                                 ushort_t* __restrict__ w256) {
    int idx = blockIdx.x * 256 + threadIdx.x;   // 65536
    float qv = qw[idx], ov = ow[idx];
    ushort_t qh = bf16rne(qv);
    w256[idx] = qh;
    w256[idx + 65536] = bf16rne(qv - ubf(qh));
    ushort_t oh = bf16rne(ov);
    w256[idx + 131072] = oh;
    w256[idx + 196608] = bf16rne(ov - ubf(oh));
}

// ---------------------------------------------------------------------------
// 2. conv5x5 (512->256) as 25 shifted MFMA GEMMs, bf16 2-way split.
//    R5 structure: 224 blocks = 28u x 8ntcs (XCD-affine weight slices);
//    512 thr = 8 waves (2wm x 4wn); wave = 4mf x 2nf; LDS pitch 32us + XOR
//    slot swizzle; T14 async-stage for A.  NEW: fragment-major B layout ->
//    every B load is 1KB contiguous per wave (was 16-segment gather).
__global__ __launch_bounds__(512) void k_conv_mfma(const uint_t* __restrict__ rec,
                                                   const ushort_t* __restrict__ wrep_hi,
                                                   float* __restrict__ hpart) {
    const int bid = blockIdx.x;
    const int ntcs = bid & 7;
    const int u = bid >> 3;              // 0..27
    const int mt = u % 7;
    const int b  = u / 7;
    const int nt = ntcs & 1;
    const int cs = ntcs >> 1;

    const int tid  = threadIdx.x;
    const int lane = tid & 63;
    const int wid  = tid >> 6;
    const int wm = wid & 1, wn = wid >> 1;    // 2 pos-groups x 4 oc-groups
    const int m_in = lane & 15, g = lane >> 4;

    const int p0  = mt * 128;
    const int ylo = p0 / 28;

    // sA: hi [320 plin][32 c] (XOR-swizzled 16B slots), lo at +10240
    __shared__ __align__(16) ushort_t sA[20480];

    int plinb[4];
    #pragma unroll
    for (int mf = 0; mf < 4; ++mf) {
        int p = p0 + wm * 64 + mf * 16 + m_in;
        int y = p / 28, xx = p - y * 28;
        plinb[mf] = (y - ylo) * 32 + xx;
    }

    const int oc0 = nt * 128 + wn * 32;
    const int ocf0 = nt * 8 + wn * 2;        // oc-fragment index base
    const ushort_t* bp[2];
    #pragma unroll
    for (int nf = 0; nf < 2; ++nf)
        bp[nf] = wrep_hi + (size_t)(ocf0 + nf) * 8192 + (lane << 3);

    f32x4 acc[4][2];
    #pragma unroll
    for (int i = 0; i < 4; ++i)
        #pragma unroll
        for (int j = 0; j < 2; ++j)
            acc[i][j] = (f32x4){0.f, 0.f, 0.f, 0.f};

    // --- staging slot descriptors: slot it handles flat v = tid + 512*it,
    //     valid while v < 1280 (it<2 always; it==2 only for tid<256).
    int  s_pl[3], s_cg[3];
    bool s_ok[3];
    const uint_t* s_rp[3];
    #pragma unroll
    for (int it = 0; it < 3; ++it) {
        int v  = tid + it * 512;
        bool valid = (v < 1280);
        int cg = v & 3, pl = v >> 2;      // pl 0..319
        int ty = pl >> 5, tx = pl & 31;
        int yi = ylo - 2 + ty, xi = tx - 2;
        bool ok = valid && (yi >= 0) && (yi < 28) && (xi >= 0) && (xi < 28);
        s_pl[it] = pl; s_cg[it] = cg; s_ok[it] = ok;
        int off = ok ? (yi * 28 + xi) : 0;
        s_rp[it] = rec + ((size_t)(b * 512 + cg * 8)) * NPOS + off;
    }
    uint_t st[3][8];

#define STAGE_LOAD(CB) do {                                                  \
    _Pragma("unroll")                                                        \
    for (int it_ = 0; it_ < 3; ++it_) {                                      \
        if (it_ < 2 || tid < 256) {                                          \
            const uint_t* rp_ = s_rp[it_] + (size_t)(CB) * NPOS;             \
            _Pragma("unroll")                                                \
            for (int i_ = 0; i_ < 8; ++i_)                                   \
                st[it_][i_] = s_ok[it_] ? rp_[(size_t)i_ * NPOS] : 0u;       \
        } } } while (0)

#define STAGE_WRITE() do {                                                   \
    _Pragma("unroll")                                                        \
    for (int it_ = 0; it_ < 3; ++it_) {                                      \
        if (it_ < 2 || tid < 256) {                                          \
            uint_t hw_[4], lw_[4];                                           \
            _Pragma("unroll")                                                \
            for (int j_ = 0; j_ < 4; ++j_) {                                 \
                hw_[j_] = (st[it_][2*j_] >> 16) | (st[it_][2*j_+1] & 0xFFFF0000u); \
                lw_[j_] = (st[it_][2*j_] & 0xFFFFu) | (st[it_][2*j_+1] << 16);     \
            }                                                                \
            int pl_ = s_pl[it_];                                             \
            int cw_ = s_cg[it_] ^ ((pl_ >> 1) & 3);                          \
            *(uint4*)(sA + pl_ * 32 + cw_ * 8) =                             \
                make_uint4(hw_[0], hw_[1], hw_[2], hw_[3]);                  \
            *(uint4*)(sA + 10240 + pl_ * 32 + cw_ * 8) =                     \
                make_uint4(lw_[0], lw_[1], lw_[2], lw_[3]);                  \
        } } } while (0)

#define LOADB(BH, BL, TAP, CBI) do {                                         \
    size_t tof_ = (size_t)(TAP) * 131072 + (size_t)(CBI) * 512;              \
    _Pragma("unroll")                                                        \
    for (int nf_ = 0; nf_ < 2; ++nf_) {                                      \
        BH[nf_] = *(const bf16x8*)(bp[nf_] + tof_);                          \
        BL[nf_] = *(const bf16x8*)(bp[nf_] + tof_ + 3276800u);               \
    } } while (0)

#define TAPBODY(BH, BL, TOFF) do {                                           \
    int to_ = (TOFF);                                                        \
    _Pragma("unroll")                                                        \
    for (int mf_ = 0; mf_ < 4; ++mf_) {                                      \
        const int pl_ = plinb[mf_] + to_;                                    \
        const int ao_ = (pl_ << 5) + ((g ^ ((pl_ >> 1) & 3)) << 3);          \
        bf16x8 ah_ = *(const bf16x8*)(sA + ao_);                             \
        bf16x8 al_ = *(const bf16x8*)(sA + 10240 + ao_);                     \
        _Pragma("unroll")                                                    \
        for (int nf_ = 0; nf_ < 2; ++nf_) {                                  \
            acc[mf_][nf_] = __builtin_amdgcn_mfma_f32_16x16x32_bf16(         \
                ah_, BH[nf_], acc[mf_][nf_], 0, 0, 0);                       \
            acc[mf_][nf_] = __builtin_amdgcn_mfma_f32_16x16x32_bf16(         \
                ah_, BL[nf_], acc[mf_][nf_], 0, 0, 0);                       \
            acc[mf_][nf_] = __builtin_amdgcn_mfma_f32_16x16x32_bf16(         \
                al_, BH[nf_], acc[mf_][nf_], 0, 0, 0);                       \
        } } } while (0)

    STAGE_LOAD(cs * 128);                 // chunk 0 loads in flight

    for (int ch = 0; ch < 4; ++ch) {
        const int cb  = cs * 128 + ch * 32;
        const int cbi = cs * 4 + ch;      // 32-c block index for B layout

        __syncthreads();                  // buffer free (prev chunk reads done)
        STAGE_WRITE();                    // ds_write chunk ch (loads returned)
        __syncthreads();                  // buffer ready
        if (ch < 3) STAGE_LOAD(cb + 32);  // issue next chunk loads early (T14)

        bf16x8 bh0[2], bl0[2], bh1[2], bl1[2];
        LOADB(bh0, bl0, 0, cbi);
        for (int t = 0; t < 24; t += 2) {
            int t1 = t + 1, t2 = (t + 2 <= 24) ? t + 2 : 24;
            LOADB(bh1, bl1, t1, cbi);
            TAPBODY(bh0, bl0, (t / 5) * 32 + (t % 5));
            LOADB(bh0, bl0, t2, cbi);
            TAPBODY(bh1, bl1, (t1 / 5) * 32 + (t1 % 5));
        }
        TAPBODY(bh0, bl0, 4 * 32 + 4);
    }

    #pragma unroll
    for (int mf = 0; mf < 4; ++mf) {
        int prow = p0 + wm * 64 + mf * 16 + g * 4;
        #pragma unroll
        for (int nf = 0; nf < 2; ++nf) {
            int oc = oc0 + nf * 16 + m_in;
            #pragma unroll
            for (int r = 0; r < 4; ++r) {
                int pos = prow + r;
                if (pos < NPOS)
                    hpart[(((size_t)(cs * 4 + b) * NPOS + pos) << 8) + oc] =
                        acc[mf][nf][r];
            }
        }
    }
#undef STAGE_LOAD
#undef STAGE_WRITE
#undef LOADB
#undef TAPBODY
}

// ---------------------------------------------------------------------------
// 3. reduce partials + bias + channel-LN + GELU + 1x1(256->16) + tanh + clip
__global__ __launch_bounds__(256) void k_lnoff(const float* __restrict__ hpart,
                                               const float* __restrict__ b1,
                                               const float* __restrict__ g,
                                               const float* __restrict__ bb,
                                               const float* __restrict__ w2,
                                               const float* __restrict__ b2,
                                               const float* __restrict__ ref,
                                               float* __restrict__ loc) {
    const int pos = blockIdx.x, b = blockIdx.y, c = threadIdx.x;
    float v = b1[c];
    #pragma unroll
    for (int cs = 0; cs < 4; ++cs)
        v += hpart[((size_t)((cs * 4 + b) * NPOS + pos)) * 256 + c];

    float s1 = v, s2 = v * v;
    #pragma unroll
    for (int m = 32; m >= 1; m >>= 1) {
        s1 += __shfl_xor(s1, m);
        s2 += __shfl_xor(s2, m);
    }
    __shared__ float r1[4], r2[4];
    const int wv = c >> 6, ln = c & 63;
    if (ln == 0) { r1[wv] = s1; r2[wv] = s2; }
    __syncthreads();
    s1 = r1[0] + r1[1] + r1[2] + r1[3];
    s2 = r2[0] + r2[1] + r2[2] + r2[3];
    const float mu  = s1 * (1.f / 256.f);
    const float var = s2 * (1.f / 256.f) - mu * mu;
    const float rstd = 1.f / sqrtf(var + 1e-5f);
    const float xn = (v - mu) * rstd * g[c] + bb[c];
    const float ge = 0.5f * xn * (1.f + erff(xn * 0.70710678118654752f));

    __shared__ float ro[4][16];
    for (int o = 0; o < 16; ++o) {
        float pv = ge * w2[o * 256 + c];
        #pragma unroll
        for (int m = 32; m >= 1; m >>= 1) pv += __shfl_xor(pv, m);
        if (ln == 0) ro[wv][o] = pv;
    }
    __syncthreads();
    if (c < 16) {
        float off = ro[0][c] + ro[1][c] + ro[2][c] + ro[3][c] + b2[c];
        float t = tanhf(off);
        int hd = c >> 1, comp = c & 1;
        size_t li = ((size_t)((b * 8 + hd) * NPOS + pos)) * 2 + comp;
        float l = ref[li] + t;
        loc[li] = fminf(1.f, fmaxf(-1.f, l));
    }
}

// ---------------------------------------------------------------------------
// 4. bilinear grid_sample, zeros padding -> samp[32][32][784].
__global__ __launch_bounds__(256) void k_gsample(const float* __restrict__ x,
                                                 const float* __restrict__ loc,
                                                 float* __restrict__ samp) {
    int idx = blockIdx.x * 256 + threadIdx.x;      // 25,088 exact
    int pos = idx % NPOS;
    int bh  = idx / NPOS;
    float gx = loc[(size_t)idx * 2 + 0];
    float gy = loc[(size_t)idx * 2 + 1];
    float ix = (gx + 1.f) * 28.f - 0.5f;
    float iy = (gy + 1.f) * 28.f - 0.5f;
    float x0f = floorf(ix), y0f = floorf(iy);
    int x0 = (int)x0f, y0 = (int)y0f;
    float wx = ix - x0f, wy = iy - y0f;

    int xs[2] = { x0, x0 + 1 };
    int ys[2] = { y0, y0 + 1 };
    float wxs[2] = { 1.f - wx, wx };
    float wys[2] = { 1.f - wy, wy };
    int   cidx[4];
    float cw[4];
    #pragma unroll
    for (int a = 0; a < 2; ++a)
        #pragma unroll
        for (int bb2 = 0; bb2 < 2; ++bb2) {
            int yy = ys[a], xx = xs[bb2];
            bool inb = (xx >= 0) && (xx < W_) && (yy >= 0) && (yy < H_);
            int yyc = min(max(yy, 0), H_ - 1), xxc = min(max(xx, 0), W_ - 1);
            cidx[a * 2 + bb2] = yyc * W_ + xxc;
            cw[a * 2 + bb2] = inb ? (wys[a] * wxs[bb2]) : 0.f;
        }

    const float* xb = x + (size_t)bh * DPH * NS;
    #pragma unroll 4
    for (int c = 0; c < DPH; ++c) {
        const float* xc = xb + (size_t)c * NS;
        float v = cw[0] * xc[cidx[0]] + cw[1] * xc[cidx[1]]
                + cw[2] * xc[cidx[2]] + cw[3] * xc[cidx[3]];
        samp[((size_t)bh * DPH + c) * NPOS + pos] = v;
    }
}

// ---------------------------------------------------------------------------
// 4b. qpe = (query + pos_emb) transposed to [b][s][256] packed-split u32.
__global__ __launch_bounds__(256) void k_qpe(const float* __restrict__ q,
                                             const float* __restrict__ pe,
                                             uint_t* __restrict__ qpe) {
    const int st = blockIdx.x, b = blockIdx.y;
    const int s0 = st * 64;
    __shared__ uint_t T[64 * 129];
    const int l = threadIdx.x & 63, w = threadIdx.x >> 6;

    for (int half = 0; half < 2; ++half) {
        #pragma unroll 4
        for (int cc = 0; cc < 32; ++cc) {
            int c = half * 128 + w * 32 + cc;
            size_t gi = (size_t)(b * 256 + c) * NS + s0 + l;
            T[l * 129 + w * 32 + cc] = packsplit(q[gi] + pe[gi]);
        }
        __syncthreads();
        {
            int s = threadIdx.x >> 2, q4 = threadIdx.x & 3;
            uint_t* dst = qpe + ((size_t)b * NS + s0 + s) * 256 + half * 128 + q4 * 32;
            const uint_t* src = T + s * 129 + q4 * 32;
            #pragma unroll
            for (int i = 0; i < 8; ++i) {
                uint_t a0 = src[i * 4], a1 = src[i * 4 + 1];
                uint_t a2 = src[i * 4 + 2], a3 = src[i * 4 + 3];
                *(uint4*)(dst + i * 4) = make_uint4(a0, a1, a2, a3);
            }
        }
        __syncthreads();
    }
}

// ---------------------------------------------------------------------------
// 5. streaming MFMA 256x256 projection, wave = 2mf x 2nf (32oc x 32s).
//    grid (49, 4, 4) = 784 blocks, 3136 waves. NS = 49*64 exact -> no guards.
//    MODE 0: out bf16 [b][s][256] (+bias); MODE 1: out f32 [b][256][3136].
template<int MODE>
__global__ __launch_bounds__(256) void k_proj(const uint_t* __restrict__ inT,
                                              const ushort_t* __restrict__ wh,
                                              const ushort_t* __restrict__ wl,
                                              const float* __restrict__ bias,
                                              float* __restrict__ outf,
                                              ushort_t* __restrict__ outb) {
    const int st = blockIdx.x, og = blockIdx.y, b = blockIdx.z;
    const int tid = threadIdx.x, lane = tid & 63, wid = tid >> 6;
    const int wsg = wid & 1, wo = wid >> 1;
    const int n = lane & 15, g = lane >> 4;
    const int s0 = st * 64 + wsg * 32;
    const int oc0 = og * 64 + wo * 32;
    const uint_t* ibase = inT + (size_t)b * NS * 256;

    f32x4 acc[2][2];
    #pragma unroll
    for (int i = 0; i < 2; ++i)
        #pragma unroll
        for (int j = 0; j < 2; ++j)
            acc[i][j] = (f32x4){0.f, 0.f, 0.f, 0.f};

    #pragma unroll 2
    for (int kf = 0; kf < 8; ++kf) {
        const int ko = kf * 32 + g * 8;
        bf16x8 awh[2], awl[2];
        #pragma unroll
        for (int mf = 0; mf < 2; ++mf) {
            size_t a = (size_t)(oc0 + mf * 16 + n) * 256 + ko;
            awh[mf] = *(const bf16x8*)(wh + a);
            awl[mf] = *(const bf16x8*)(wl + a);
        }
        bf16x8 bh[2], bl[2];
        #pragma unroll
        for (int nf = 0; nf < 2; ++nf) {
            const uint4* p = (const uint4*)(ibase + (size_t)(s0 + nf * 16 + n) * 256 + ko);
            uint4 u = p[0], v = p[1];
            bh[nf] = mk8((u.x >> 16) | (u.y & 0xFFFF0000u),
                         (u.z >> 16) | (u.w & 0xFFFF0000u),
                         (v.x >> 16) | (v.y & 0xFFFF0000u),
                         (v.z >> 16) | (v.w & 0xFFFF0000u));
            bl[nf] = mk8((u.x & 0xFFFFu) | (u.y << 16),
                         (u.z & 0xFFFFu) | (u.w << 16),
                         (v.x & 0xFFFFu) | (v.y << 16),
                         (v.z & 0xFFFFu) | (v.w << 16));
        }
        #pragma unroll
        for (int mf = 0; mf < 2; ++mf)
            #pragma unroll
            for (int nf = 0; nf < 2; ++nf) {
                acc[mf][nf] = __builtin_amdgcn_mfma_f32_16x16x32_bf16(
                    awh[mf], bh[nf], acc[mf][nf], 0, 0, 0);
                acc[mf][nf] = __builtin_amdgcn_mfma_f32_16x16x32_bf16(
                    awh[mf], bl[nf], acc[mf][nf], 0, 0, 0);
                acc[mf][nf] = __builtin_amdgcn_mfma_f32_16x16x32_bf16(
                    awl[mf], bh[nf], acc[mf][nf], 0, 0, 0);
            }
    }

    #pragma unroll
    for (int mf = 0; mf < 2; ++mf) {
        const int ocr = oc0 + mf * 16 + g * 4;
        float bs[4];
        #pragma unroll
        for (int r = 0; r < 4; ++r) bs[r] = bias[ocr + r];
        #pragma unroll
        for (int nf = 0; nf < 2; ++nf) {
            int sc = s0 + nf * 16 + n;
            if (MODE == 0) {
                uint_t p0 = (uint_t)bf16rne(acc[mf][nf][0] + bs[0])
                          | ((uint_t)bf16rne(acc[mf][nf][1] + bs[1]) << 16);
                uint_t p1 = (uint_t)bf16rne(acc[mf][nf][2] + bs[2])
                          | ((uint_t)bf16rne(acc[mf][nf][3] + bs[3]) << 16);
                *(uint2*)(outb + ((size_t)b * NS + sc) * 256 + ocr) =
                    make_uint2(p0, p1);
            } else {
                #pragma unroll
                for (int r = 0; r < 4; ++r)
                    outf[(size_t)(b * 256 + ocr + r) * NS + sc] =
                        acc[mf][nf][r] + bs[r];
            }
        }
    }
}

// ---------------------------------------------------------------------------
// 6. k/v 32->32 projections -> bf16: ktb[bh][pos][32], vtb[bh][dph][pos].
__global__ __launch_bounds__(256) void k_kv(const float* __restrict__ samp,
                                            const float* __restrict__ kw,
                                            const float* __restrict__ kb,
                                            const float* __restrict__ vw,
                                            const float* __restrict__ vb,
                                            ushort_t* __restrict__ ktb,
                                            ushort_t* __restrict__ vtb) {
    __shared__ __align__(16) float kl[1024], vl[1024];
    const int tid = threadIdx.x;
    for (int i = tid; i < 1024; i += 256) {
        int o = i >> 5, c = i & 31;
        kl[c * 32 + o] = kw[i];
        vl[c * 32 + o] = vw[i];
    }
    __syncthreads();
    int idx = blockIdx.x * 256 + tid;   // 25,088 exact
    int pos = idx % NPOS;
    int bh  = idx / NPOS;
    const float* sp = samp + (size_t)bh * DPH * NPOS + pos;
    float ak[32] = {}, av[32] = {};
    for (int c = 0; c < 32; ++c) {
        float sv = sp[(size_t)c * NPOS];
        #pragma unroll
        for (int og = 0; og < 8; ++og) {
            float4 k4 = *(const float4*)&kl[c * 32 + og * 4];
            float4 v4 = *(const float4*)&vl[c * 32 + og * 4];
            ak[og * 4 + 0] = fmaf(sv, k4.x, ak[og * 4 + 0]);
            ak[og * 4 + 1] = fmaf(sv, k4.y, ak[og * 4 + 1]);
            ak[og * 4 + 2] = fmaf(sv, k4.z, ak[og * 4 + 2]);
            ak[og * 4 + 3] = fmaf(sv, k4.w, ak[og * 4 + 3]);
            av[og * 4 + 0] = fmaf(sv, v4.x, av[og * 4 + 0]);
            av[og * 4 + 1] = fmaf(sv, v4.y, av[og * 4 + 1]);
            av[og * 4 + 2] = fmaf(sv, v4.z, av[og * 4 + 2]);
            av[og * 4 + 3] = fmaf(sv, v4.w, av[og * 4 + 3]);
        }
    }
    uint_t kp[16];
    #pragma unroll
    for (int o = 0; o < 16; ++o)
        kp[o] = (uint_t)bf16rne(ak[2 * o] + kb[2 * o])
              | ((uint_t)bf16rne(ak[2 * o + 1] + kb[2 * o + 1]) << 16);
    uint4* kdst = (uint4*)(ktb + (size_t)idx * 32);
    kdst[0] = make_uint4(kp[0], kp[1], kp[2], kp[3]);
    kdst[1] = make_uint4(kp[4], kp[5], kp[6], kp[7]);
    kdst[2] = make_uint4(kp[8], kp[9], kp[10], kp[11]);
    kdst[3] = make_uint4(kp[12], kp[13], kp[14], kp[15]);
    #pragma unroll
    for (int o = 0; o < 32; ++o)
        vtb[((size_t)bh * 32 + o) * NPOS + pos] = bf16rne(av[o] + vb[o]);
}

// ---------------------------------------------------------------------------
// 7. MFMA flash attention. grid (25 qtile, 32 bh), 256 thr = 4 waves.
//    Wave = 32 q rows (2 nf frags); K/V frags direct from global; no barriers.
__global__ __launch_bounds__(256) void k_attn_mfma(const ushort_t* __restrict__ qbf,
                                                   const ushort_t* __restrict__ ktb,
                                                   const ushort_t* __restrict__ vtb,
                                                   uint_t* __restrict__ attnT) {
    const int qt = blockIdx.x, bh = blockIdx.y;
    const int b = bh >> 3, head = bh & 7;
    const int tid = threadIdx.x, lane = tid & 63, wid = tid >> 6;
    const int n = lane & 15, g = lane >> 4;

    __shared__ __align__(16) ushort_t sP[4][32 * 72];    // per-wave [q][kv], pad 72

    const int q0 = qt * 128 + wid * 32;

    bf16x8 qf[2];
    #pragma unroll
    for (int nf = 0; nf < 2; ++nf) {
        int srow = min(q0 + nf * 16 + n, NS - 1);
        qf[nf] = *(const bf16x8*)(qbf + ((size_t)b * NS + srow) * 256 + head * 32 + g * 8);
    }

    const ushort_t* kbase = ktb + (size_t)bh * NPOS * 32;
    const ushort_t* vbase = vtb + (size_t)bh * 32 * NPOS;
    ushort_t* myP = sP[wid];

    f32x4 o_acc[2][2];
    #pragma unroll
    for (int i = 0; i < 2; ++i)
        #pragma unroll
        for (int j = 0; j < 2; ++j)
            o_acc[i][j] = (f32x4){0.f, 0.f, 0.f, 0.f};
    float mrun[2] = {-1e30f, -1e30f};
    float lrun[2] = {0.f, 0.f};

    for (int t = 0; t < 12; ++t) {
        const int kvt = t * 64;
        bf16x8 kf[4];
        #pragma unroll
        for (int mf = 0; mf < 4; ++mf)
            kf[mf] = *(const bf16x8*)(kbase + (size_t)(kvt + mf * 16 + n) * 32 + g * 8);
        bf16x8 vf[2][2];
        #pragma unroll
        for (int mv = 0; mv < 2; ++mv)
            #pragma unroll
            for (int kc = 0; kc < 2; ++kc)
                vf[mv][kc] = *(const bf16x8*)(vbase + (size_t)(mv * 16 + n) * NPOS
                                              + kvt + kc * 32 + g * 8);

        f32x4 acc[4][2];
        #pragma unroll
        for (int mf = 0; mf < 4; ++mf)
            #pragma unroll
            for (int nf = 0; nf < 2; ++nf)
                acc[mf][nf] = __builtin_amdgcn_mfma_f32_16x16x32_bf16(
                    kf[mf], qf[nf], (f32x4){0.f, 0.f, 0.f, 0.f}, 0, 0, 0);

        #pragma unroll
        for (int nf = 0; nf < 2; ++nf) {
            float s[4][4];
            float tmax = -1e30f;
            #pragma unroll
            for (int mf = 0; mf < 4; ++mf)
                #pragma unroll
                for (int r = 0; r < 4; ++r) {
                    s[mf][r] = acc[mf][nf][r] * (1.f / 16.f);
                    tmax = fmaxf(tmax, s[mf][r]);
                }
            tmax = fmaxf(tmax, __shfl_xor(tmax, 16));
            tmax = fmaxf(tmax, __shfl_xor(tmax, 32));
            float mnew = fmaxf(mrun[nf], tmax);
            float corr = __expf(mrun[nf] - mnew);
            mrun[nf] = mnew;
            float psum = 0.f;
            float p[4][4];
            #pragma unroll
            for (int mf = 0; mf < 4; ++mf)
                #pragma unroll
                for (int r = 0; r < 4; ++r) {
                    p[mf][r] = __expf(s[mf][r] - mnew);
                    psum += p[mf][r];
                }
            psum += __shfl_xor(psum, 16);
            psum += __shfl_xor(psum, 32);
            lrun[nf] = lrun[nf] * corr + psum;
            #pragma unroll
            for (int mv = 0; mv < 2; ++mv)
                #pragma unroll
                for (int r = 0; r < 4; ++r)
                    o_acc[mv][nf][r] *= corr;
            #pragma unroll
            for (int mf = 0; mf < 4; ++mf) {
                uint_t lo = cvtpk_bf16(p[mf][0], p[mf][1]);
                uint_t hi = cvtpk_bf16(p[mf][2], p[mf][3]);
                *(uint2*)(myP + (nf * 16 + n) * 72 + mf * 16 + g * 4) =
                    make_uint2(lo, hi);
            }
        }

        #pragma unroll
        for (int kc = 0; kc < 2; ++kc)
            #pragma unroll
            for (int nf = 0; nf < 2; ++nf) {
                bf16x8 pb = *(const bf16x8*)(myP + (nf * 16 + n) * 72
                                             + kc * 32 + g * 8);
                #pragma unroll
                for (int mv = 0; mv < 2; ++mv)
                    o_acc[mv][nf] = __builtin_amdgcn_mfma_f32_16x16x32_bf16(
                        vf[mv][kc], pb, o_acc[mv][nf], 0, 0, 0);
            }
    }

    // epilog tile: kv 768..783
    {
        const int kvt = 768;
        bf16x8 kf0 = *(const bf16x8*)(kbase + (size_t)(kvt + n) * 32 + g * 8);
        bf16x8 vf[2];
        int kvo = kvt + g * 8; if (kvo > 776) kvo = 776;
        #pragma unroll
        for (int mv = 0; mv < 2; ++mv)
            vf[mv] = *(const bf16x8*)(vbase + (size_t)(mv * 16 + n) * NPOS + kvo);

        f32x4 acc0[2];
        #pragma unroll
        for (int nf = 0; nf < 2; ++nf)
            acc0[nf] = __builtin_amdgcn_mfma_f32_16x16x32_bf16(
                kf0, qf[nf], (f32x4){0.f, 0.f, 0.f, 0.f}, 0, 0, 0);

        #pragma unroll
        for (int nf = 0; nf < 2; ++nf) {
            float s[4], tmax = -1e30f;
            #pragma unroll
            for (int r = 0; r < 4; ++r) {
                s[r] = acc0[nf][r] * (1.f / 16.f);
                tmax = fmaxf(tmax, s[r]);
            }
            tmax = fmaxf(tmax, __shfl_xor(tmax, 16));
            tmax = fmaxf(tmax, __shfl_xor(tmax, 32));
            float mnew = fmaxf(mrun[nf], tmax);
            float corr = __expf(mrun[nf] - mnew);
            mrun[nf] = mnew;
            float psum = 0.f, p[4];
            #pragma unroll
            for (int r = 0; r < 4; ++r) { p[r] = __expf(s[r] - mnew); psum += p[r]; }
            psum += __shfl_xor(psum, 16);
            psum += __shfl_xor(psum, 32);
            lrun[nf] = lrun[nf] * corr + psum;
            #pragma unroll
            for (int mv = 0; mv < 2; ++mv)
                #pragma unroll
                for (int r = 0; r < 4; ++r)
                    o_acc[mv][nf][r] *= corr;
            uint_t lo = cvtpk_bf16(p[0], p[1]);
            uint_t hi = cvtpk_bf16(p[2], p[3]);
            *(uint2*)(myP + (nf * 16 + n) * 72 + g * 4) = make_uint2(lo, hi);
            *(uint2*)(myP + (nf * 16 + n) * 72 + 16 + g * 4) = make_uint2(0u, 0u);
        }
        #pragma unroll
        for (int nf = 0; nf < 2; ++nf) {
            bf16x8 pb = *(const bf16x8*)(myP + (nf * 16 + n) * 72 + g * 8);
            #pragma unroll
            for (int mv = 0; mv < 2; ++mv)
                o_acc[mv][nf] = __builtin_amdgcn_mfma_f32_16x16x32_bf16(
                    vf[mv], pb, o_acc[mv][nf], 0, 0, 0);
        }
    }

    // normalize + store attnT packed-split [b][s][256]
    #pragma unroll
    for (int nf = 0; nf < 2; ++nf) {
        float inv = 1.f / lrun[nf];
        int qpos = q0 + nf * 16 + n;
        if (qpos < NS) {
            #pragma unroll
            for (int mv = 0; mv < 2; ++mv) {
                uint_t pk[4];
                #pragma unroll
                for (int r = 0; r < 4; ++r)
                    pk[r] = packsplit(o_acc[mv][nf][r] * inv);
                *(uint4*)(attnT + ((size_t)b * NS + qpos) * 256
                          + head * 32 + mv * 16 + g * 4) =
                    make_uint4(pk[0], pk[1], pk[2], pk[3]);
            }
        }
    }
}

// ---------------------------------------------------------------------------
extern "C" void kernel_launch(void* const* d_in, const int* in_sizes, int n_in,
                              void* d_out, int out_size, void* d_ws, size_t ws_size,
                              hipStream_t stream) {
    const float* query = (const float*)d_in[0];
    const float* x     = (const float*)d_in[1];
    const float* refp  = (const float*)d_in[2];
    const float* pe    = (const float*)d_in[3];
    const float* w1    = (const float*)d_in[4];
    const float* b1    = (const float*)d_in[5];
    const float* lng   = (const float*)d_in[6];
    const float* lnb   = (const float*)d_in[7];
    const float* w2    = (const float*)d_in[8];
    const float* b2    = (const float*)d_in[9];
    const float* qw    = (const float*)d_in[10];
    const float* qb    = (const float*)d_in[11];
    const float* kw    = (const float*)d_in[12];
    const float* kb    = (const float*)d_in[13];
    const float* vw    = (const float*)d_in[14];
    const float* vb    = (const float*)d_in[15];
    const float* ow    = (const float*)d_in[16];
    const float* ob    = (const float*)d_in[17];

    float* ws  = (float*)d_ws;
    float* out = (float*)d_out;

    uint_t*   rec    = (uint_t*)(ws + OFF_REC);
    float*    hpart  = ws + OFF_HPART;
    float*    loc    = ws + OFF_LOC;
    float*    samp   = ws + OFF_SAMP;
    ushort_t* ktb    = (ushort_t*)(ws + OFF_KTB);
    ushort_t* vtb    = (ushort_t*)(ws + OFF_VTB);
    ushort_t* w256   = (ushort_t*)(ws + OFF_W256);
    ushort_t* wrep_hi = (ushort_t*)(ws + OFF_WREPC);
    uint_t*   qpe    = (uint_t*)(ws + OFF_QPE);     // alias WREPC (dead after conv)
    ushort_t* qbf    = (ushort_t*)(ws + OFF_QBF);   // alias REC (dead after conv)
    uint_t*   attnT  = (uint_t*)(ws + OFF_ATTNT);   // alias HPART (dead after lnoff)

    ushort_t* qwh = w256;
    ushort_t* qwl = w256 + 65536;
    ushort_t* owh = w256 + 131072;
    ushort_t* owl = w256 + 196608;

    k_pool<<<6272, 256, 0, stream>>>(query, x, rec);
    k_wrepack<<<1600, 256, 0, stream>>>(w1, wrep_hi, wrep_hi + 3276800u);
    k_wrep256<<<256, 256, 0, stream>>>(qw, ow, w256);
    k_conv_mfma<<<224, 512, 0, stream>>>(rec, wrep_hi, hpart);
    k_lnoff<<<dim3(784, 4), 256, 0, stream>>>(hpart, b1, lng, lnb, w2, b2, refp, loc);
    k_gsample<<<98, 256, 0, stream>>>(x, loc, samp);
    k_qpe<<<dim3(49, 4), 256, 0, stream>>>(query, pe, qpe);
    k_proj<0><<<dim3(49, 4, 4), 256, 0, stream>>>(qpe, qwh, qwl, qb, nullptr, qbf);
    k_kv<<<98, 256, 0, stream>>>(samp, kw, kb, vw, vb, ktb, vtb);
    k_attn_mfma<<<dim3(25, 32), 256, 0, stream>>>(qbf, ktb, vtb, attnT);
    k_proj<1><<<dim3(49, 4, 4), 256, 0, stream>>>(attnT, owh, owl, ob, out, nullptr);
}

// Round 9
// 216.899 us; speedup vs baseline: 1.7282x; 1.1751x over previous
//
#include <hip/hip_runtime.h>
#include <hip/hip_bf16.h>

// Problem constants
#define B_    4
#define D_    256
#define H_    56
#define W_    56
#define NH_   28
#define NW_   28
#define HEADS 8
#define DPH   32
#define NPOS  784      // 28*28
#define NS    3136     // 56*56
#define NSB   196      // NS/16 sblocks

typedef unsigned short ushort_t;
typedef unsigned int uint_t;
typedef __attribute__((ext_vector_type(8))) short bf16x8;
typedef __attribute__((ext_vector_type(4))) float f32x4;

// ws layout (float offsets)
#define OFF_REC     0u          // packed u32 [4][512][784]      1,605,632
#define OFF_HPART   1605632u    // f32 [4cs][4b][784][256]       3,211,264
#define OFF_WREPC   4816896u    // conv wrep hi+lo (6,553,600 us) 3,276,800
#define OFF_LOC     8093696u    // f32 [32][784][2]              50,176
#define OFF_SAMP    8143872u    // f32 [32][32][784]             802,816
#define OFF_KTB     8946688u    // bf16 [32][784][32]            401,408
#define OFF_VTB     9348096u    // bf16 [32][32][784]+pad        401,472
#define OFF_W256    9749568u    // qw/ow hi+lo fm (262,144 us)   131,072
// aliases (lifetime-disjoint):
#define OFF_QPE     4816896u    // fm u32 [4][196][8][64][8] (alias WREPC, dead after conv)
#define OFF_QBF     0u          // fm bf16 [4][196][8][64][8] (alias REC, dead after conv)
#define OFF_ATTNT   1605632u    // fm u32 [4][196][8][64][8] (alias HPART, dead after lnoff)
// total 9,880,640 floats = 39.5 MB

__device__ __forceinline__ ushort_t bf16rne(float f) {
    uint_t u = __float_as_uint(f);
    return (ushort_t)((u + 0x7FFFu + ((u >> 16) & 1u)) >> 16);
}
__device__ __forceinline__ float ubf(ushort_t h) {
    return __uint_as_float(((uint_t)h) << 16);
}
__device__ __forceinline__ uint_t packsplit(float v) {
    ushort_t hi = bf16rne(v);
    ushort_t lo = bf16rne(v - ubf(hi));
    return ((uint_t)hi << 16) | (uint_t)lo;
}
__device__ __forceinline__ uint_t cvtpk_bf16(float a, float b) {
    uint_t r;
    asm("v_cvt_pk_bf16_f32 %0, %1, %2" : "=v"(r) : "v"(a), "v"(b));
    return r;
}
__device__ __forceinline__ bf16x8 mk8(uint_t a, uint_t b, uint_t c, uint_t d) {
    union { uint_t u[4]; bf16x8 v; } x;
    x.u[0] = a; x.u[1] = b; x.u[2] = c; x.u[3] = d;
    return x.v;
}

// ---------------------------------------------------------------------------
// 1. 2x2 avg-pool of query|x -> rec packed-split u32 [4][512][784]
__global__ __launch_bounds__(256) void k_pool(const float* __restrict__ q,
                                              const float* __restrict__ x,
                                              uint_t* __restrict__ rec) {
    int idx = blockIdx.x * 256 + threadIdx.x;      // 1,605,632 exact
    int j = idx % NW_;
    int i = (idx / NW_) % NH_;
    int c = (idx / NPOS) % 512;
    int b = idx / (NPOS * 512);
    const float* src = (c < 256) ? q : x;
    int cc = (c < 256) ? c : (c - 256);
    const float* p = src + ((size_t)(b * 256 + cc) * H_ + i * 2) * W_ + j * 2;
    float v = 0.25f * (p[0] + p[1] + p[W_] + p[W_ + 1]);
    rec[idx] = packsplit(v);
}

// ---------------------------------------------------------------------------
// 1b. repack conv weights FRAGMENT-MAJOR:
//     wrep[tap][ocf(16)][cbi(16)][lane(64)][8] bf16 hi (lo at +3,276,800).
__global__ __launch_bounds__(256) void k_wrepack(const float* __restrict__ w1,
                                                 ushort_t* __restrict__ wh,
                                                 ushort_t* __restrict__ wl) {
    int idx = blockIdx.x * 256 + threadIdx.x;   // 409,600
    int lane = idx & 63;
    int cbi  = (idx >> 6) & 15;
    int ocf  = (idx >> 10) & 15;
    int tap  = idx >> 14;                        // 0..24
    int m_in = lane & 15, g = lane >> 4;
    int oc = ocf * 16 + m_in;
    int c0 = cbi * 32 + g * 8;
    const float* wp = w1 + ((size_t)oc * 512 + c0) * 25 + tap;
    uint_t hp[4], lp[4];
    #pragma unroll
    for (int j = 0; j < 4; ++j) {
        float v0 = wp[(size_t)(2 * j) * 25];
        float v1 = wp[(size_t)(2 * j + 1) * 25];
        ushort_t h0 = bf16rne(v0), h1 = bf16rne(v1);
        ushort_t l0 = bf16rne(v0 - ubf(h0)), l1 = bf16rne(v1 - ubf(h1));
        hp[j] = (uint_t)h0 | ((uint_t)h1 << 16);
        lp[j] = (uint_t)l0 | ((uint_t)l1 << 16);
    }
    *(uint4*)(wh + (size_t)idx * 8) = make_uint4(hp[0], hp[1], hp[2], hp[3]);
    *(uint4*)(wl + (size_t)idx * 8) = make_uint4(lp[0], lp[1], lp[2], lp[3]);
}

// 1c. repack q_w and o_w FRAGMENT-MAJOR: [ocf(16)][cbi(8)][lane(64)][8] hi/lo.
__global__ __launch_bounds__(256) void k_wrep256(const float* __restrict__ qw,
                                                 const float* __restrict__ ow,
                                                 ushort_t* __restrict__ w256) {
    int idx = blockIdx.x * 256 + threadIdx.x;   // 8192 = ocf*512 + cbi*64 + lane
    int lane = idx & 63;
    int cbi  = (idx >> 6) & 7;
    int ocf  = idx >> 9;                         // 0..15
    int n = lane & 15, g = lane >> 4;
    size_t src = (size_t)(ocf * 16 + n) * 256 + cbi * 32 + g * 8;
    uint_t qh[4], ql[4], oh[4], ol[4];
    #pragma unroll
    for (int j = 0; j < 4; ++j) {
        float q0 = qw[src + 2 * j], q1 = qw[src + 2 * j + 1];
        float o0 = ow[src + 2 * j], o1 = ow[src + 2 * j + 1];
        ushort_t qh0 = bf16rne(q0), qh1 = bf16rne(q1);
        ushort_t oh0 = bf16rne(o0), oh1 = bf16rne(o1);
        qh[j] = (uint_t)qh0 | ((uint_t)qh1 << 16);
        ql[j] = (uint_t)bf16rne(q0 - ubf(qh0)) | ((uint_t)bf16rne(q1 - ubf(qh1)) << 16);
        oh[j] = (uint_t)oh0 | ((uint_t)oh1 << 16);
        ol[j] = (uint_t)bf16rne(o0 - ubf(oh0)) | ((uint_t)bf16rne(o1 - ubf(oh1)) << 16);
    }
    size_t dst = (size_t)idx * 8;
    *(uint4*)(w256 + dst)          = make_uint4(qh[0], qh[1], qh[2], qh[3]);
    *(uint4*)(w256 + dst + 65536)  = make_uint4(ql[0], ql[1], ql[2], ql[3]);
    *(uint4*)(w256 + dst + 131072) = make_uint4(oh[0], oh[1], oh[2], oh[3]);
    *(uint4*)(w256 + dst + 196608) = make_uint4(ol[0], ol[1], ol[2], ol[3]);
}

// ---------------------------------------------------------------------------
// 2. conv5x5 (512->256) as 25 shifted MFMA GEMMs — unchanged from R7 (73 us).
__global__ __launch_bounds__(512) void k_conv_mfma(const uint_t* __restrict__ rec,
                                                   const ushort_t* __restrict__ wrep_hi,
                                                   float* __restrict__ hpart) {
    const int bid = blockIdx.x;
    const int ntcs = bid & 7;
    const int u = bid >> 3;              // 0..27
    const int mt = u % 7;
    const int b  = u / 7;
    const int nt = ntcs & 1;
    const int cs = ntcs >> 1;

    const int tid  = threadIdx.x;
    const int lane = tid & 63;
    const int wid  = tid >> 6;
    const int wm = wid & 1, wn = wid >> 1;    // 2 pos-groups x 4 oc-groups
    const int m_in = lane & 15, g = lane >> 4;

    const int p0  = mt * 128;
    const int ylo = p0 / 28;

    __shared__ __align__(16) ushort_t sA[20480];

    int plinb[4];
    #pragma unroll
    for (int mf = 0; mf < 4; ++mf) {
        int p = p0 + wm * 64 + mf * 16 + m_in;
        int y = p / 28, xx = p - y * 28;
        plinb[mf] = (y - ylo) * 32 + xx;
    }

    const int oc0 = nt * 128 + wn * 32;
    const int ocf0 = nt * 8 + wn * 2;
    const ushort_t* bp[2];
    #pragma unroll
    for (int nf = 0; nf < 2; ++nf)
        bp[nf] = wrep_hi + (size_t)(ocf0 + nf) * 8192 + (lane << 3);

    f32x4 acc[4][2];
    #pragma unroll
    for (int i = 0; i < 4; ++i)
        #pragma unroll
        for (int j = 0; j < 2; ++j)
            acc[i][j] = (f32x4){0.f, 0.f, 0.f, 0.f};

    int  s_pl[3], s_cg[3];
    bool s_ok[3];
    const uint_t* s_rp[3];
    #pragma unroll
    for (int it = 0; it < 3; ++it) {
        int v  = tid + it * 512;
        bool valid = (v < 1280);
        int cg = v & 3, pl = v >> 2;
        int ty = pl >> 5, tx = pl & 31;
        int yi = ylo - 2 + ty, xi = tx - 2;
        bool ok = valid && (yi >= 0) && (yi < 28) && (xi >= 0) && (xi < 28);
        s_pl[it] = pl; s_cg[it] = cg; s_ok[it] = ok;
        int off = ok ? (yi * 28 + xi) : 0;
        s_rp[it] = rec + ((size_t)(b * 512 + cg * 8)) * NPOS + off;
    }
    uint_t st[3][8];

#define STAGE_LOAD(CB) do {                                                  \
    _Pragma("unroll")                                                        \
    for (int it_ = 0; it_ < 3; ++it_) {                                      \
        if (it_ < 2 || tid < 256) {                                          \
            const uint_t* rp_ = s_rp[it_] + (size_t)(CB) * NPOS;             \
            _Pragma("unroll")                                                \
            for (int i_ = 0; i_ < 8; ++i_)                                   \
                st[it_][i_] = s_ok[it_] ? rp_[(size_t)i_ * NPOS] : 0u;       \
        } } } while (0)

#define STAGE_WRITE() do {                                                   \
    _Pragma("unroll")                                                        \
    for (int it_ = 0; it_ < 3; ++it_) {                                      \
        if (it_ < 2 || tid < 256) {                                          \
            uint_t hw_[4], lw_[4];                                           \
            _Pragma("unroll")                                                \
            for (int j_ = 0; j_ < 4; ++j_) {                                 \
                hw_[j_] = (st[it_][2*j_] >> 16) | (st[it_][2*j_+1] & 0xFFFF0000u); \
                lw_[j_] = (st[it_][2*j_] & 0xFFFFu) | (st[it_][2*j_+1] << 16);     \
            }                                                                \
            int pl_ = s_pl[it_];                                             \
            int cw_ = s_cg[it_] ^ ((pl_ >> 1) & 3);                          \
            *(uint4*)(sA + pl_ * 32 + cw_ * 8) =                             \
                make_uint4(hw_[0], hw_[1], hw_[2], hw_[3]);                  \
            *(uint4*)(sA + 10240 + pl_ * 32 + cw_ * 8) =                     \
                make_uint4(lw_[0], lw_[1], lw_[2], lw_[3]);                  \
        } } } while (0)

#define LOADB(BH, BL, TAP, CBI) do {                                         \
    size_t tof_ = (size_t)(TAP) * 131072 + (size_t)(CBI) * 512;              \
    _Pragma("unroll")                                                        \
    for (int nf_ = 0; nf_ < 2; ++nf_) {                                      \
        BH[nf_] = *(const bf16x8*)(bp[nf_] + tof_);                          \
        BL[nf_] = *(const bf16x8*)(bp[nf_] + tof_ + 3276800u);               \
    } } while (0)

#define TAPBODY(BH, BL, TOFF) do {                                           \
    int to_ = (TOFF);                                                        \
    _Pragma("unroll")                                                        \
    for (int mf_ = 0; mf_ < 4; ++mf_) {                                      \
        const int pl_ = plinb[mf_] + to_;                                    \
        const int ao_ = (pl_ << 5) + ((g ^ ((pl_ >> 1) & 3)) << 3);          \
        bf16x8 ah_ = *(const bf16x8*)(sA + ao_);                             \
        bf16x8 al_ = *(const bf16x8*)(sA + 10240 + ao_);                     \
        _Pragma("unroll")                                                    \
        for (int nf_ = 0; nf_ < 2; ++nf_) {                                  \
            acc[mf_][nf_] = __builtin_amdgcn_mfma_f32_16x16x32_bf16(         \
                ah_, BH[nf_], acc[mf_][nf_], 0, 0, 0);                       \
            acc[mf_][nf_] = __builtin_amdgcn_mfma_f32_16x16x32_bf16(         \
                ah_, BL[nf_], acc[mf_][nf_], 0, 0, 0);                       \
            acc[mf_][nf_] = __builtin_amdgcn_mfma_f32_16x16x32_bf16(         \
                al_, BH[nf_], acc[mf_][nf_], 0, 0, 0);                       \
        } } } while (0)

    STAGE_LOAD(cs * 128);

    for (int ch = 0; ch < 4; ++ch) {
        const int cb  = cs * 128 + ch * 32;
        const int cbi = cs * 4 + ch;

        __syncthreads();
        STAGE_WRITE();
        __syncthreads();
        if (ch < 3) STAGE_LOAD(cb + 32);

        bf16x8 bh0[2], bl0[2], bh1[2], bl1[2];
        LOADB(bh0, bl0, 0, cbi);
        for (int t = 0; t < 24; t += 2) {
            int t1 = t + 1, t2 = (t + 2 <= 24) ? t + 2 : 24;
            LOADB(bh1, bl1, t1, cbi);
            TAPBODY(bh0, bl0, (t / 5) * 32 + (t % 5));
            LOADB(bh0, bl0, t2, cbi);
            TAPBODY(bh1, bl1, (t1 / 5) * 32 + (t1 % 5));
        }
        TAPBODY(bh0, bl0, 4 * 32 + 4);
    }

    #pragma unroll
    for (int mf = 0; mf < 4; ++mf) {
        int prow = p0 + wm * 64 + mf * 16 + g * 4;
        #pragma unroll
        for (int nf = 0; nf < 2; ++nf) {
            int oc = oc0 + nf * 16 + m_in;
            #pragma unroll
            for (int r = 0; r < 4; ++r) {
                int pos = prow + r;
                if (pos < NPOS)
                    hpart[(((size_t)(cs * 4 + b) * NPOS + pos) << 8) + oc] =
                        acc[mf][nf][r];
            }
        }
    }
#undef STAGE_LOAD
#undef STAGE_WRITE
#undef LOADB
#undef TAPBODY
}

// ---------------------------------------------------------------------------
// 3. reduce partials + bias + channel-LN + GELU + 1x1(256->16) + tanh + clip
__global__ __launch_bounds__(256) void k_lnoff(const float* __restrict__ hpart,
                                               const float* __restrict__ b1,
                                               const float* __restrict__ g,
                                               const float* __restrict__ bb,
                                               const float* __restrict__ w2,
                                               const float* __restrict__ b2,
                                               const float* __restrict__ ref,
                                               float* __restrict__ loc) {
    const int pos = blockIdx.x, b = blockIdx.y, c = threadIdx.x;
    float v = b1[c];
    #pragma unroll
    for (int cs = 0; cs < 4; ++cs)
        v += hpart[((size_t)((cs * 4 + b) * NPOS + pos)) * 256 + c];

    float s1 = v, s2 = v * v;
    #pragma unroll
    for (int m = 32; m >= 1; m >>= 1) {
        s1 += __shfl_xor(s1, m);
        s2 += __shfl_xor(s2, m);
    }
    __shared__ float r1[4], r2[4];
    const int wv = c >> 6, ln = c & 63;
    if (ln == 0) { r1[wv] = s1; r2[wv] = s2; }
    __syncthreads();
    s1 = r1[0] + r1[1] + r1[2] + r1[3];
    s2 = r2[0] + r2[1] + r2[2] + r2[3];
    const float mu  = s1 * (1.f / 256.f);
    const float var = s2 * (1.f / 256.f) - mu * mu;
    const float rstd = 1.f / sqrtf(var + 1e-5f);
    const float xn = (v - mu) * rstd * g[c] + bb[c];
    const float ge = 0.5f * xn * (1.f + erff(xn * 0.70710678118654752f));

    __shared__ float ro[4][16];
    for (int o = 0; o < 16; ++o) {
        float pv = ge * w2[o * 256 + c];
        #pragma unroll
        for (int m = 32; m >= 1; m >>= 1) pv += __shfl_xor(pv, m);
        if (ln == 0) ro[wv][o] = pv;
    }
    __syncthreads();
    if (c < 16) {
        float off = ro[0][c] + ro[1][c] + ro[2][c] + ro[3][c] + b2[c];
        float t = tanhf(off);
        int hd = c >> 1, comp = c & 1;
        size_t li = ((size_t)((b * 8 + hd) * NPOS + pos)) * 2 + comp;
        float l = ref[li] + t;
        loc[li] = fminf(1.f, fmaxf(-1.f, l));
    }
}

// ---------------------------------------------------------------------------
// 4. bilinear grid_sample, zeros padding -> samp[32][32][784].
__global__ __launch_bounds__(256) void k_gsample(const float* __restrict__ x,
                                                 const float* __restrict__ loc,
                                                 float* __restrict__ samp) {
    int idx = blockIdx.x * 256 + threadIdx.x;      // 25,088 exact
    int pos = idx % NPOS;
    int bh  = idx / NPOS;
    float gx = loc[(size_t)idx * 2 + 0];
    float gy = loc[(size_t)idx * 2 + 1];
    float ix = (gx + 1.f) * 28.f - 0.5f;
    float iy = (gy + 1.f) * 28.f - 0.5f;
    float x0f = floorf(ix), y0f = floorf(iy);
    int x0 = (int)x0f, y0 = (int)y0f;
    float wx = ix - x0f, wy = iy - y0f;

    int xs[2] = { x0, x0 + 1 };
    int ys[2] = { y0, y0 + 1 };
    float wxs[2] = { 1.f - wx, wx };
    float wys[2] = { 1.f - wy, wy };
    int   cidx[4];
    float cw[4];
    #pragma unroll
    for (int a = 0; a < 2; ++a)
        #pragma unroll
        for (int bb2 = 0; bb2 < 2; ++bb2) {
            int yy = ys[a], xx = xs[bb2];
            bool inb = (xx >= 0) && (xx < W_) && (yy >= 0) && (yy < H_);
            int yyc = min(max(yy, 0), H_ - 1), xxc = min(max(xx, 0), W_ - 1);
            cidx[a * 2 + bb2] = yyc * W_ + xxc;
            cw[a * 2 + bb2] = inb ? (wys[a] * wxs[bb2]) : 0.f;
        }

    const float* xb = x + (size_t)bh * DPH * NS;
    #pragma unroll 4
    for (int c = 0; c < DPH; ++c) {
        const float* xc = xb + (size_t)c * NS;
        float v = cw[0] * xc[cidx[0]] + cw[1] * xc[cidx[1]]
                + cw[2] * xc[cidx[2]] + cw[3] * xc[cidx[3]];
        samp[((size_t)bh * DPH + c) * NPOS + pos] = v;
    }
}

// ---------------------------------------------------------------------------
// 4b. qpe = (query + pos_emb) -> FRAGMENT-MAJOR packed-split u32
//     [b][sblk(196)][cblk(8)][lane(64)][8]; lane=g*16+n holds
//     (s=sblk*16+n, c=cblk*32+g*8+e).
__global__ __launch_bounds__(256) void k_qpe(const float* __restrict__ q,
                                             const float* __restrict__ pe,
                                             uint_t* __restrict__ qpe) {
    const int st = blockIdx.x, b = blockIdx.y;
    const int s0 = st * 64;
    __shared__ uint_t T[64 * 129];
    const int l = threadIdx.x & 63, w = threadIdx.x >> 6;

    for (int half = 0; half < 2; ++half) {
        #pragma unroll 4
        for (int cc = 0; cc < 32; ++cc) {
            int c = half * 128 + w * 32 + cc;
            size_t gi = (size_t)(b * 256 + c) * NS + s0 + l;
            T[l * 129 + w * 32 + cc] = packsplit(q[gi] + pe[gi]);
        }
        __syncthreads();
        #pragma unroll
        for (int it = 0; it < 4; ++it) {
            int u2 = threadIdx.x + it * 256;     // 0..1023
            int sblk = u2 >> 8;                  // 0..3
            int cbl  = (u2 >> 6) & 3;            // local cblk 0..3
            int lane = u2 & 63;
            int n = lane & 15, g = lane >> 4;
            const uint_t* src = T + (sblk * 16 + n) * 129 + cbl * 32 + g * 8;
            uint_t* dst = qpe + ((((size_t)b * NSB + st * 4 + sblk) * 8
                                  + half * 4 + cbl) * 64 + lane) * 8;
            *(uint4*)dst       = make_uint4(src[0], src[1], src[2], src[3]);
            *(uint4*)(dst + 4) = make_uint4(src[4], src[5], src[6], src[7]);
        }
        __syncthreads();
    }
}

// ---------------------------------------------------------------------------
// 5. streaming MFMA 256x256 projection — fragment-major in/out.
//    A = weights fm [ocf][cbi][lane][8] hi/lo; B = input fm u32.
//    MODE 0: out bf16 FRAGMENT-MAJOR [b][sblk][cblk][lane][8] (+bias) -> attn Q
//    MODE 1: out f32 [b][256][3136] (+bias) -> d_out
template<int MODE>
__global__ __launch_bounds__(256) void k_proj(const uint_t* __restrict__ inT,
                                              const ushort_t* __restrict__ wh,
                                              const ushort_t* __restrict__ wl,
                                              const float* __restrict__ bias,
                                              float* __restrict__ outf,
                                              ushort_t* __restrict__ outb) {
    const int st = blockIdx.x, og = blockIdx.y, b = blockIdx.z;
    const int tid = threadIdx.x, lane = tid & 63, wid = tid >> 6;
    const int wsg = wid & 1, wo = wid >> 1;
    const int n = lane & 15, g = lane >> 4;
    const int s0 = st * 64 + wsg * 32;
    const int sb0 = s0 >> 4;                   // sblk base (nf adds 1)
    const int oc0 = og * 64 + wo * 32;
    const int ocf0 = oc0 >> 4;                 // ocf base (mf adds 1)

    f32x4 acc[2][2];
    #pragma unroll
    for (int i = 0; i < 2; ++i)
        #pragma unroll
        for (int j = 0; j < 2; ++j)
            acc[i][j] = (f32x4){0.f, 0.f, 0.f, 0.f};

    #pragma unroll 2
    for (int kf = 0; kf < 8; ++kf) {
        bf16x8 awh[2], awl[2];
        #pragma unroll
        for (int mf = 0; mf < 2; ++mf) {
            size_t a = (((size_t)(ocf0 + mf) * 8 + kf) * 64 + lane) * 8;
            awh[mf] = *(const bf16x8*)(wh + a);
            awl[mf] = *(const bf16x8*)(wl + a);
        }
        bf16x8 bh[2], bl[2];
        #pragma unroll
        for (int nf = 0; nf < 2; ++nf) {
            const uint_t* p = inT + ((((size_t)b * NSB + sb0 + nf) * 8 + kf) * 64 + lane) * 8;
            uint4 u = *(const uint4*)p, v = *(const uint4*)(p + 4);
            bh[nf] = mk8((u.x >> 16) | (u.y & 0xFFFF0000u),
                         (u.z >> 16) | (u.w & 0xFFFF0000u),
                         (v.x >> 16) | (v.y & 0xFFFF0000u),
                         (v.z >> 16) | (v.w & 0xFFFF0000u));
            bl[nf] = mk8((u.x & 0xFFFFu) | (u.y << 16),
                         (u.z & 0xFFFFu) | (u.w << 16),
                         (v.x & 0xFFFFu) | (v.y << 16),
                         (v.z & 0xFFFFu) | (v.w << 16));
        }
        #pragma unroll
        for (int mf = 0; mf < 2; ++mf)
            #pragma unroll
            for (int nf = 0; nf < 2; ++nf) {
                acc[mf][nf] = __builtin_amdgcn_mfma_f32_16x16x32_bf16(
                    awh[mf], bh[nf], acc[mf][nf], 0, 0, 0);
                acc[mf][nf] = __builtin_amdgcn_mfma_f32_16x16x32_bf16(
                    awh[mf], bl[nf], acc[mf][nf], 0, 0, 0);
                acc[mf][nf] = __builtin_amdgcn_mfma_f32_16x16x32_bf16(
                    awl[mf], bh[nf], acc[mf][nf], 0, 0, 0);
            }
    }

    #pragma unroll
    for (int mf = 0; mf < 2; ++mf) {
        const int ocr = oc0 + mf * 16 + g * 4;
        float bs[4];
        #pragma unroll
        for (int r = 0; r < 4; ++r) bs[r] = bias[ocr + r];
        #pragma unroll
        for (int nf = 0; nf < 2; ++nf) {
            if (MODE == 0) {
                // fm write: cblk = oc0>>5, lane2 = (mf*2 + g/2)*16 + n, e = (g&1)*4
                const int cblk = oc0 >> 5;
                const int lane2 = (mf * 2 + (g >> 1)) * 16 + n;
                uint_t p0 = (uint_t)bf16rne(acc[mf][nf][0] + bs[0])
                          | ((uint_t)bf16rne(acc[mf][nf][1] + bs[1]) << 16);
                uint_t p1 = (uint_t)bf16rne(acc[mf][nf][2] + bs[2])
                          | ((uint_t)bf16rne(acc[mf][nf][3] + bs[3]) << 16);
                *(uint2*)(outb + (((size_t)b * NSB + sb0 + nf) * 8 + cblk) * 512
                          + lane2 * 8 + (g & 1) * 4) = make_uint2(p0, p1);
            } else {
                int sc = s0 + nf * 16 + n;
                #pragma unroll
                for (int r = 0; r < 4; ++r)
                    outf[(size_t)(b * 256 + ocr + r) * NS + sc] =
                        acc[mf][nf][r] + bs[r];
            }
        }
    }
}

// ---------------------------------------------------------------------------
// 6. k/v 32->32 projections -> bf16: ktb[bh][pos][32], vtb[bh][dph][pos].
__global__ __launch_bounds__(256) void k_kv(const float* __restrict__ samp,
                                            const float* __restrict__ kw,
                                            const float* __restrict__ kb,
                                            const float* __restrict__ vw,
                                            const float* __restrict__ vb,
                                            ushort_t* __restrict__ ktb,
                                            ushort_t* __restrict__ vtb) {
    __shared__ __align__(16) float kl[1024], vl[1024];
    const int tid = threadIdx.x;
    for (int i = tid; i < 1024; i += 256) {
        int o = i >> 5, c = i & 31;
        kl[c * 32 + o] = kw[i];
        vl[c * 32 + o] = vw[i];
    }
    __syncthreads();
    int idx = blockIdx.x * 256 + tid;   // 25,088 exact
    int pos = idx % NPOS;
    int bh  = idx / NPOS;
    const float* sp = samp + (size_t)bh * DPH * NPOS + pos;
    float ak[32] = {}, av[32] = {};
    for (int c = 0; c < 32; ++c) {
        float sv = sp[(size_t)c * NPOS];
        #pragma unroll
        for (int og = 0; og < 8; ++og) {
            float4 k4 = *(const float4*)&kl[c * 32 + og * 4];
            float4 v4 = *(const float4*)&vl[c * 32 + og * 4];
            ak[og * 4 + 0] = fmaf(sv, k4.x, ak[og * 4 + 0]);
            ak[og * 4 + 1] = fmaf(sv, k4.y, ak[og * 4 + 1]);
            ak[og * 4 + 2] = fmaf(sv, k4.z, ak[og * 4 + 2]);
            ak[og * 4 + 3] = fmaf(sv, k4.w, ak[og * 4 + 3]);
            av[og * 4 + 0] = fmaf(sv, v4.x, av[og * 4 + 0]);
            av[og * 4 + 1] = fmaf(sv, v4.y, av[og * 4 + 1]);
            av[og * 4 + 2] = fmaf(sv, v4.z, av[og * 4 + 2]);
            av[og * 4 + 3] = fmaf(sv, v4.w, av[og * 4 + 3]);
        }
    }
    uint_t kp[16];
    #pragma unroll
    for (int o = 0; o < 16; ++o)
        kp[o] = (uint_t)bf16rne(ak[2 * o] + kb[2 * o])
              | ((uint_t)bf16rne(ak[2 * o + 1] + kb[2 * o + 1]) << 16);
    uint4* kdst = (uint4*)(ktb + (size_t)idx * 32);
    kdst[0] = make_uint4(kp[0], kp[1], kp[2], kp[3]);
    kdst[1] = make_uint4(kp[4], kp[5], kp[6], kp[7]);
    kdst[2] = make_uint4(kp[8], kp[9], kp[10], kp[11]);
    kdst[3] = make_uint4(kp[12], kp[13], kp[14], kp[15]);
    #pragma unroll
    for (int o = 0; o < 32; ++o)
        vtb[((size_t)bh * 32 + o) * NPOS + pos] = bf16rne(av[o] + vb[o]);
}

// ---------------------------------------------------------------------------
// 7. MFMA flash attention. grid (25 qtile, 32 bh), 256 thr = 4 waves.
//    Q from fragment-major qbf (contiguous 1KB loads); output attnT
//    fragment-major u32 for the streaming o-proj.
__global__ __launch_bounds__(256) void k_attn_mfma(const ushort_t* __restrict__ qbf,
                                                   const ushort_t* __restrict__ ktb,
                                                   const ushort_t* __restrict__ vtb,
                                                   uint_t* __restrict__ attnT) {
    const int qt = blockIdx.x, bh = blockIdx.y;
    const int b = bh >> 3, head = bh & 7;
    const int tid = threadIdx.x, lane = tid & 63, wid = tid >> 6;
    const int n = lane & 15, g = lane >> 4;

    __shared__ __align__(16) ushort_t sP[4][32 * 72];    // per-wave [q][kv], pad 72

    const int q0 = qt * 128 + wid * 32;

    bf16x8 qf[2];
    #pragma unroll
    for (int nf = 0; nf < 2; ++nf) {
        int sb = min(q0 / 16 + nf, NSB - 1);
        qf[nf] = *(const bf16x8*)(qbf + ((((size_t)b * NSB + sb) * 8 + head) * 64 + lane) * 8);
    }

    const ushort_t* kbase = ktb + (size_t)bh * NPOS * 32;
    const ushort_t* vbase = vtb + (size_t)bh * 32 * NPOS;
    ushort_t* myP = sP[wid];

    f32x4 o_acc[2][2];
    #pragma unroll
    for (int i = 0; i < 2; ++i)
        #pragma unroll
        for (int j = 0; j < 2; ++j)
            o_acc[i][j] = (f32x4){0.f, 0.f, 0.f, 0.f};
    float mrun[2] = {-1e30f, -1e30f};
    float lrun[2] = {0.f, 0.f};

    for (int t = 0; t < 12; ++t) {
        const int kvt = t * 64;
        bf16x8 kf[4];
        #pragma unroll
        for (int mf = 0; mf < 4; ++mf)
            kf[mf] = *(const bf16x8*)(kbase + (size_t)(kvt + mf * 16 + n) * 32 + g * 8);
        bf16x8 vf[2][2];
        #pragma unroll
        for (int mv = 0; mv < 2; ++mv)
            #pragma unroll
            for (int kc = 0; kc < 2; ++kc)
                vf[mv][kc] = *(const bf16x8*)(vbase + (size_t)(mv * 16 + n) * NPOS
                                              + kvt + kc * 32 + g * 8);

        f32x4 acc[4][2];
        #pragma unroll
        for (int mf = 0; mf < 4; ++mf)
            #pragma unroll
            for (int nf = 0; nf < 2; ++nf)
                acc[mf][nf] = __builtin_amdgcn_mfma_f32_16x16x32_bf16(
                    kf[mf], qf[nf], (f32x4){0.f, 0.f, 0.f, 0.f}, 0, 0, 0);

        #pragma unroll
        for (int nf = 0; nf < 2; ++nf) {
            float s[4][4];
            float tmax = -1e30f;
            #pragma unroll
            for (int mf = 0; mf < 4; ++mf)
                #pragma unroll
                for (int r = 0; r < 4; ++r) {
                    s[mf][r] = acc[mf][nf][r] * (1.f / 16.f);
                    tmax = fmaxf(tmax, s[mf][r]);
                }
            tmax = fmaxf(tmax, __shfl_xor(tmax, 16));
            tmax = fmaxf(tmax, __shfl_xor(tmax, 32));
            float mnew = fmaxf(mrun[nf], tmax);
            float corr = __expf(mrun[nf] - mnew);
            mrun[nf] = mnew;
            float psum = 0.f;
            float p[4][4];
            #pragma unroll
            for (int mf = 0; mf < 4; ++mf)
                #pragma unroll
                for (int r = 0; r < 4; ++r) {
                    p[mf][r] = __expf(s[mf][r] - mnew);
                    psum += p[mf][r];
                }
            psum += __shfl_xor(psum, 16);
            psum += __shfl_xor(psum, 32);
            lrun[nf] = lrun[nf] * corr + psum;
            #pragma unroll
            for (int mv = 0; mv < 2; ++mv)
                #pragma unroll
                for (int r = 0; r < 4; ++r)
                    o_acc[mv][nf][r] *= corr;
            #pragma unroll
            for (int mf = 0; mf < 4; ++mf) {
                uint_t lo = cvtpk_bf16(p[mf][0], p[mf][1]);
                uint_t hi = cvtpk_bf16(p[mf][2], p[mf][3]);
                *(uint2*)(myP + (nf * 16 + n) * 72 + mf * 16 + g * 4) =
                    make_uint2(lo, hi);
            }
        }

        #pragma unroll
        for (int kc = 0; kc < 2; ++kc)
            #pragma unroll
            for (int nf = 0; nf < 2; ++nf) {
                bf16x8 pb = *(const bf16x8*)(myP + (nf * 16 + n) * 72
                                             + kc * 32 + g * 8);
                #pragma unroll
                for (int mv = 0; mv < 2; ++mv)
                    o_acc[mv][nf] = __builtin_amdgcn_mfma_f32_16x16x32_bf16(
                        vf[mv][kc], pb, o_acc[mv][nf], 0, 0, 0);
            }
    }

    // epilog tile: kv 768..783
    {
        const int kvt = 768;
        bf16x8 kf0 = *(const bf16x8*)(kbase + (size_t)(kvt + n) * 32 + g * 8);
        bf16x8 vf[2];
        int kvo = kvt + g * 8; if (kvo > 776) kvo = 776;
        #pragma unroll
        for (int mv = 0; mv < 2; ++mv)
            vf[mv] = *(const bf16x8*)(vbase + (size_t)(mv * 16 + n) * NPOS + kvo);

        f32x4 acc0[2];
        #pragma unroll
        for (int nf = 0; nf < 2; ++nf)
            acc0[nf] = __builtin_amdgcn_mfma_f32_16x16x32_bf16(
                kf0, qf[nf], (f32x4){0.f, 0.f, 0.f, 0.f}, 0, 0, 0);

        #pragma unroll
        for (int nf = 0; nf < 2; ++nf) {
            float s[4], tmax = -1e30f;
            #pragma unroll
            for (int r = 0; r < 4; ++r) {
                s[r] = acc0[nf][r] * (1.f / 16.f);
                tmax = fmaxf(tmax, s[r]);
            }
            tmax = fmaxf(tmax, __shfl_xor(tmax, 16));
            tmax = fmaxf(tmax, __shfl_xor(tmax, 32));
            float mnew = fmaxf(mrun[nf], tmax);
            float corr = __expf(mrun[nf] - mnew);
            mrun[nf] = mnew;
            float psum = 0.f, p[4];
            #pragma unroll
            for (int r = 0; r < 4; ++r) { p[r] = __expf(s[r] - mnew); psum += p[r]; }
            psum += __shfl_xor(psum, 16);
            psum += __shfl_xor(psum, 32);
            lrun[nf] = lrun[nf] * corr + psum;
            #pragma unroll
            for (int mv = 0; mv < 2; ++mv)
                #pragma unroll
                for (int r = 0; r < 4; ++r)
                    o_acc[mv][nf][r] *= corr;
            uint_t lo = cvtpk_bf16(p[0], p[1]);
            uint_t hi = cvtpk_bf16(p[2], p[3]);
            *(uint2*)(myP + (nf * 16 + n) * 72 + g * 4) = make_uint2(lo, hi);
            *(uint2*)(myP + (nf * 16 + n) * 72 + 16 + g * 4) = make_uint2(0u, 0u);
        }
        #pragma unroll
        for (int nf = 0; nf < 2; ++nf) {
            bf16x8 pb = *(const bf16x8*)(myP + (nf * 16 + n) * 72 + g * 8);
            #pragma unroll
            for (int mv = 0; mv < 2; ++mv)
                o_acc[mv][nf] = __builtin_amdgcn_mfma_f32_16x16x32_bf16(
                    vf[mv], pb, o_acc[mv][nf], 0, 0, 0);
        }
    }

    // normalize + store attnT FRAGMENT-MAJOR packed-split u32:
    // element (s=qpos, c=head*32+mv*16+g*4+r) -> [b][sblk][head][lane2][e]
    // lane2 = (mv*2 + g/2)*16 + n, e = (g&1)*4 + r  (uint4 per (nf,mv)).
    #pragma unroll
    for (int nf = 0; nf < 2; ++nf) {
        if (q0 + nf * 16 < NS) {
            float inv = 1.f / lrun[nf];
            const size_t sbase = (((size_t)b * NSB + (q0 / 16 + nf)) * 8 + head) * 512;
            #pragma unroll
            for (int mv = 0; mv < 2; ++mv) {
                uint_t pk[4];
                #pragma unroll
                for (int r = 0; r < 4; ++r)
                    pk[r] = packsplit(o_acc[mv][nf][r] * inv);
                const int lane2 = (mv * 2 + (g >> 1)) * 16 + n;
                *(uint4*)(attnT + sbase + lane2 * 8 + (g & 1) * 4) =
                    make_uint4(pk[0], pk[1], pk[2], pk[3]);
            }
        }
    }
}

// ---------------------------------------------------------------------------
extern "C" void kernel_launch(void* const* d_in, const int* in_sizes, int n_in,
                              void* d_out, int out_size, void* d_ws, size_t ws_size,
                              hipStream_t stream) {
    const float* query = (const float*)d_in[0];
    const float* x     = (const float*)d_in[1];
    const float* refp  = (const float*)d_in[2];
    const float* pe    = (const float*)d_in[3];
    const float* w1    = (const float*)d_in[4];
    const float* b1    = (const float*)d_in[5];
    const float* lng   = (const float*)d_in[6];
    const float* lnb   = (const float*)d_in[7];
    const float* w2    = (const float*)d_in[8];
    const float* b2    = (const float*)d_in[9];
    const float* qw    = (const float*)d_in[10];
    const float* qb    = (const float*)d_in[11];
    const float* kw    = (const float*)d_in[12];
    const float* kb    = (const float*)d_in[13];
    const float* vw    = (const float*)d_in[14];
    const float* vb    = (const float*)d_in[15];
    const float* ow    = (const float*)d_in[16];
    const float* ob    = (const float*)d_in[17];

    float* ws  = (float*)d_ws;
    float* out = (float*)d_out;

    uint_t*   rec    = (uint_t*)(ws + OFF_REC);
    float*    hpart  = ws + OFF_HPART;
    float*    loc    = ws + OFF_LOC;
    float*    samp   = ws + OFF_SAMP;
    ushort_t* ktb    = (ushort_t*)(ws + OFF_KTB);
    ushort_t* vtb    = (ushort_t*)(ws + OFF_VTB);
    ushort_t* w256   = (ushort_t*)(ws + OFF_W256);
    ushort_t* wrep_hi = (ushort_t*)(ws + OFF_WREPC);
    uint_t*   qpe    = (uint_t*)(ws + OFF_QPE);     // alias WREPC (dead after conv)
    ushort_t* qbf    = (ushort_t*)(ws + OFF_QBF);   // alias REC (dead after conv)
    uint_t*   attnT  = (uint_t*)(ws + OFF_ATTNT);   // alias HPART (dead after lnoff)

    ushort_t* qwh = w256;
    ushort_t* qwl = w256 + 65536;
    ushort_t* owh = w256 + 131072;
    ushort_t* owl = w256 + 196608;

    k_pool<<<6272, 256, 0, stream>>>(query, x, rec);
    k_wrepack<<<1600, 256, 0, stream>>>(w1, wrep_hi, wrep_hi + 3276800u);
    k_wrep256<<<32, 256, 0, stream>>>(qw, ow, w256);
    k_conv_mfma<<<224, 512, 0, stream>>>(rec, wrep_hi, hpart);
    k_lnoff<<<dim3(784, 4), 256, 0, stream>>>(hpart, b1, lng, lnb, w2, b2, refp, loc);
    k_gsample<<<98, 256, 0, stream>>>(x, loc, samp);
    k_qpe<<<dim3(49, 4), 256, 0, stream>>>(query, pe, qpe);
    k_proj<0><<<dim3(49, 4, 4), 256, 0, stream>>>(qpe, qwh, qwl, qb, nullptr, qbf);
    k_kv<<<98, 256, 0, stream>>>(samp, kw, kb, vw, vb, ktb, vtb);
    k_attn_mfma<<<dim3(25, 32), 256, 0, stream>>>(qbf, ktb, vtb, attnT);
    k_proj<1><<<dim3(49, 4, 4), 256, 0, stream>>>(attnT, owh, owl, ob, out, nullptr);
}

// Round 10
// 202.865 us; speedup vs baseline: 1.8478x; 1.0692x over previous
//
#include <hip/hip_runtime.h>
#include <hip/hip_bf16.h>

// Problem constants
#define B_    4
#define D_    256
#define H_    56
#define W_    56
#define NH_   28
#define NW_   28
#define HEADS 8
#define DPH   32
#define NPOS  784      // 28*28
#define NS    3136     // 56*56
#define NSB   196      // NS/16 sblocks

typedef unsigned short ushort_t;
typedef unsigned int uint_t;
typedef __attribute__((ext_vector_type(8))) short bf16x8;
typedef __attribute__((ext_vector_type(4))) float f32x4;

// ws layout (float offsets)
#define OFF_REC     0u          // packed u32 [4][512][784]      1,605,632
#define OFF_HPART   1605632u    // f32 [4cs][4b][784][256]       3,211,264
#define OFF_WREPC   4816896u    // conv wrep hi+lo (6,553,600 us) 3,276,800
#define OFF_LOC     8093696u    // f32 [32][784][2]              50,176
#define OFF_SAMP    8143872u    // (unused now)                  802,816
#define OFF_KTB     8946688u    // bf16 [32][784][32]            401,408
#define OFF_VTB     9348096u    // bf16 [32][32][784]+pad        401,472
#define OFF_W256    9749568u    // qw/ow hi+lo fm (262,144 us)   131,072
// aliases (lifetime-disjoint):
#define OFF_QPE     4816896u    // fm u32 [4][196][8][64][8] (alias WREPC, dead after conv)
#define OFF_QBF     0u          // fm bf16 [4][196][8][64][8] (alias REC, dead after conv)
#define OFF_ATTNT   1605632u    // fm u32 [4][196][8][64][8] (alias HPART, dead after lnoff)
// total 9,880,640 floats = 39.5 MB

__device__ __forceinline__ ushort_t bf16rne(float f) {
    uint_t u = __float_as_uint(f);
    return (ushort_t)((u + 0x7FFFu + ((u >> 16) & 1u)) >> 16);
}
__device__ __forceinline__ float ubf(ushort_t h) {
    return __uint_as_float(((uint_t)h) << 16);
}
__device__ __forceinline__ uint_t packsplit(float v) {
    ushort_t hi = bf16rne(v);
    ushort_t lo = bf16rne(v - ubf(hi));
    return ((uint_t)hi << 16) | (uint_t)lo;
}
__device__ __forceinline__ uint_t cvtpk_bf16(float a, float b) {
    uint_t r;
    asm("v_cvt_pk_bf16_f32 %0, %1, %2" : "=v"(r) : "v"(a), "v"(b));
    return r;
}
__device__ __forceinline__ bf16x8 mk8(uint_t a, uint_t b, uint_t c, uint_t d) {
    union { uint_t u[4]; bf16x8 v; } x;
    x.u[0] = a; x.u[1] = b; x.u[2] = c; x.u[3] = d;
    return x.v;
}

// ---------------------------------------------------------------------------
// 1. PREP mega-kernel (pool | conv-wrepack | qw/ow-wrepack) — these three
//    are mutually independent; one launch lets their blocks co-schedule
//    instead of serializing on the capture stream.
//    bid <  6272 : 2x2 avg-pool -> rec packed-split u32 [4][512][784]
//    bid <  7872 : conv weights fm [tap][ocf][cbi][lane][8] hi / lo
//    bid <  7904 : q_w/o_w fm [ocf][cbi][lane][8] hi / lo
__global__ __launch_bounds__(256) void k_prep(const float* __restrict__ q,
                                              const float* __restrict__ x,
                                              const float* __restrict__ w1,
                                              const float* __restrict__ qw,
                                              const float* __restrict__ ow,
                                              uint_t* __restrict__ rec,
                                              ushort_t* __restrict__ wh,
                                              ushort_t* __restrict__ wl,
                                              ushort_t* __restrict__ w256) {
    const int bid = blockIdx.x;
    if (bid < 6272) {
        int idx = bid * 256 + threadIdx.x;      // 1,605,632 exact
        int j = idx % NW_;
        int i = (idx / NW_) % NH_;
        int c = (idx / NPOS) % 512;
        int b = idx / (NPOS * 512);
        const float* src = (c < 256) ? q : x;
        int cc = (c < 256) ? c : (c - 256);
        const float* p = src + ((size_t)(b * 256 + cc) * H_ + i * 2) * W_ + j * 2;
        float v = 0.25f * (p[0] + p[1] + p[W_] + p[W_ + 1]);
        rec[idx] = packsplit(v);
    } else if (bid < 7872) {
        int idx = (bid - 6272) * 256 + threadIdx.x;   // 409,600
        int lane = idx & 63;
        int cbi  = (idx >> 6) & 15;
        int ocf  = (idx >> 10) & 15;
        int tap  = idx >> 14;                        // 0..24
        int m_in = lane & 15, g = lane >> 4;
        int oc = ocf * 16 + m_in;
        int c0 = cbi * 32 + g * 8;
        const float* wp = w1 + ((size_t)oc * 512 + c0) * 25 + tap;
        uint_t hp[4], lp[4];
        #pragma unroll
        for (int j = 0; j < 4; ++j) {
            float v0 = wp[(size_t)(2 * j) * 25];
            float v1 = wp[(size_t)(2 * j + 1) * 25];
            ushort_t h0 = bf16rne(v0), h1 = bf16rne(v1);
            ushort_t l0 = bf16rne(v0 - ubf(h0)), l1 = bf16rne(v1 - ubf(h1));
            hp[j] = (uint_t)h0 | ((uint_t)h1 << 16);
            lp[j] = (uint_t)l0 | ((uint_t)l1 << 16);
        }
        *(uint4*)(wh + (size_t)idx * 8) = make_uint4(hp[0], hp[1], hp[2], hp[3]);
        *(uint4*)(wl + (size_t)idx * 8) = make_uint4(lp[0], lp[1], lp[2], lp[3]);
    } else {
        int idx = (bid - 7872) * 256 + threadIdx.x;   // 8192
        int lane = idx & 63;
        int cbi  = (idx >> 6) & 7;
        int ocf  = idx >> 9;                          // 0..15
        int n = lane & 15, g = lane >> 4;
        size_t src = (size_t)(ocf * 16 + n) * 256 + cbi * 32 + g * 8;
        uint_t qh[4], ql[4], oh[4], ol[4];
        #pragma unroll
        for (int j = 0; j < 4; ++j) {
            float q0 = qw[src + 2 * j], q1 = qw[src + 2 * j + 1];
            float o0 = ow[src + 2 * j], o1 = ow[src + 2 * j + 1];
            ushort_t qh0 = bf16rne(q0), qh1 = bf16rne(q1);
            ushort_t oh0 = bf16rne(o0), oh1 = bf16rne(o1);
            qh[j] = (uint_t)qh0 | ((uint_t)qh1 << 16);
            ql[j] = (uint_t)bf16rne(q0 - ubf(qh0)) | ((uint_t)bf16rne(q1 - ubf(qh1)) << 16);
            oh[j] = (uint_t)oh0 | ((uint_t)oh1 << 16);
            ol[j] = (uint_t)bf16rne(o0 - ubf(oh0)) | ((uint_t)bf16rne(o1 - ubf(oh1)) << 16);
        }
        size_t dst = (size_t)idx * 8;
        *(uint4*)(w256 + dst)          = make_uint4(qh[0], qh[1], qh[2], qh[3]);
        *(uint4*)(w256 + dst + 65536)  = make_uint4(ql[0], ql[1], ql[2], ql[3]);
        *(uint4*)(w256 + dst + 131072) = make_uint4(oh[0], oh[1], oh[2], oh[3]);
        *(uint4*)(w256 + dst + 196608) = make_uint4(ol[0], ol[1], ol[2], ol[3]);
    }
}

// ---------------------------------------------------------------------------
// 2. conv5x5 (512->256) as 25 shifted MFMA GEMMs — unchanged (73 us, at the
//    2-barrier-structure MFMA-issue ceiling ~880 TF).
__global__ __launch_bounds__(512) void k_conv_mfma(const uint_t* __restrict__ rec,
                                                   const ushort_t* __restrict__ wrep_hi,
                                                   float* __restrict__ hpart) {
    const int bid = blockIdx.x;
    const int ntcs = bid & 7;
    const int u = bid >> 3;              // 0..27
    const int mt = u % 7;
    const int b  = u / 7;
    const int nt = ntcs & 1;
    const int cs = ntcs >> 1;

    const int tid  = threadIdx.x;
    const int lane = tid & 63;
    const int wid  = tid >> 6;
    const int wm = wid & 1, wn = wid >> 1;    // 2 pos-groups x 4 oc-groups
    const int m_in = lane & 15, g = lane >> 4;

    const int p0  = mt * 128;
    const int ylo = p0 / 28;

    __shared__ __align__(16) ushort_t sA[20480];

    int plinb[4];
    #pragma unroll
    for (int mf = 0; mf < 4; ++mf) {
        int p = p0 + wm * 64 + mf * 16 + m_in;
        int y = p / 28, xx = p - y * 28;
        plinb[mf] = (y - ylo) * 32 + xx;
    }

    const int oc0 = nt * 128 + wn * 32;
    const int ocf0 = nt * 8 + wn * 2;
    const ushort_t* bp[2];
    #pragma unroll
    for (int nf = 0; nf < 2; ++nf)
        bp[nf] = wrep_hi + (size_t)(ocf0 + nf) * 8192 + (lane << 3);

    f32x4 acc[4][2];
    #pragma unroll
    for (int i = 0; i < 4; ++i)
        #pragma unroll
        for (int j = 0; j < 2; ++j)
            acc[i][j] = (f32x4){0.f, 0.f, 0.f, 0.f};

    int  s_pl[3], s_cg[3];
    bool s_ok[3];
    const uint_t* s_rp[3];
    #pragma unroll
    for (int it = 0; it < 3; ++it) {
        int v  = tid + it * 512;
        bool valid = (v < 1280);
        int cg = v & 3, pl = v >> 2;
        int ty = pl >> 5, tx = pl & 31;
        int yi = ylo - 2 + ty, xi = tx - 2;
        bool ok = valid && (yi >= 0) && (yi < 28) && (xi >= 0) && (xi < 28);
        s_pl[it] = pl; s_cg[it] = cg; s_ok[it] = ok;
        int off = ok ? (yi * 28 + xi) : 0;
        s_rp[it] = rec + ((size_t)(b * 512 + cg * 8)) * NPOS + off;
    }
    uint_t st[3][8];

#define STAGE_LOAD(CB) do {                                                  \
    _Pragma("unroll")                                                        \
    for (int it_ = 0; it_ < 3; ++it_) {                                      \
        if (it_ < 2 || tid < 256) {                                          \
            const uint_t* rp_ = s_rp[it_] + (size_t)(CB) * NPOS;             \
            _Pragma("unroll")                                                \
            for (int i_ = 0; i_ < 8; ++i_)                                   \
                st[it_][i_] = s_ok[it_] ? rp_[(size_t)i_ * NPOS] : 0u;       \
        } } } while (0)

#define STAGE_WRITE() do {                                                   \
    _Pragma("unroll")                                                        \
    for (int it_ = 0; it_ < 3; ++it_) {                                      \
        if (it_ < 2 || tid < 256) {                                          \
            uint_t hw_[4], lw_[4];                                           \
            _Pragma("unroll")                                                \
            for (int j_ = 0; j_ < 4; ++j_) {                                 \
                hw_[j_] = (st[it_][2*j_] >> 16) | (st[it_][2*j_+1] & 0xFFFF0000u); \
                lw_[j_] = (st[it_][2*j_] & 0xFFFFu) | (st[it_][2*j_+1] << 16);     \
            }                                                                \
            int pl_ = s_pl[it_];                                             \
            int cw_ = s_cg[it_] ^ ((pl_ >> 1) & 3);                          \
            *(uint4*)(sA + pl_ * 32 + cw_ * 8) =                             \
                make_uint4(hw_[0], hw_[1], hw_[2], hw_[3]);                  \
            *(uint4*)(sA + 10240 + pl_ * 32 + cw_ * 8) =                     \
                make_uint4(lw_[0], lw_[1], lw_[2], lw_[3]);                  \
        } } } while (0)

#define LOADB(BH, BL, TAP, CBI) do {                                         \
    size_t tof_ = (size_t)(TAP) * 131072 + (size_t)(CBI) * 512;              \
    _Pragma("unroll")                                                        \
    for (int nf_ = 0; nf_ < 2; ++nf_) {                                      \
        BH[nf_] = *(const bf16x8*)(bp[nf_] + tof_);                          \
        BL[nf_] = *(const bf16x8*)(bp[nf_] + tof_ + 3276800u);               \
    } } while (0)

#define TAPBODY(BH, BL, TOFF) do {                                           \
    int to_ = (TOFF);                                                        \
    _Pragma("unroll")                                                        \
    for (int mf_ = 0; mf_ < 4; ++mf_) {                                      \
        const int pl_ = plinb[mf_] + to_;                                    \
        const int ao_ = (pl_ << 5) + ((g ^ ((pl_ >> 1) & 3)) << 3);          \
        bf16x8 ah_ = *(const bf16x8*)(sA + ao_);                             \
        bf16x8 al_ = *(const bf16x8*)(sA + 10240 + ao_);                     \
        _Pragma("unroll")                                                    \
        for (int nf_ = 0; nf_ < 2; ++nf_) {                                  \
            acc[mf_][nf_] = __builtin_amdgcn_mfma_f32_16x16x32_bf16(         \
                ah_, BH[nf_], acc[mf_][nf_], 0, 0, 0);                       \
            acc[mf_][nf_] = __builtin_amdgcn_mfma_f32_16x16x32_bf16(         \
                ah_, BL[nf_], acc[mf_][nf_], 0, 0, 0);                       \
            acc[mf_][nf_] = __builtin_amdgcn_mfma_f32_16x16x32_bf16(         \
                al_, BH[nf_], acc[mf_][nf_], 0, 0, 0);                       \
        } } } while (0)

    STAGE_LOAD(cs * 128);

    for (int ch = 0; ch < 4; ++ch) {
        const int cb  = cs * 128 + ch * 32;
        const int cbi = cs * 4 + ch;

        __syncthreads();
        STAGE_WRITE();
        __syncthreads();
        if (ch < 3) STAGE_LOAD(cb + 32);

        bf16x8 bh0[2], bl0[2], bh1[2], bl1[2];
        LOADB(bh0, bl0, 0, cbi);
        for (int t = 0; t < 24; t += 2) {
            int t1 = t + 1, t2 = (t + 2 <= 24) ? t + 2 : 24;
            LOADB(bh1, bl1, t1, cbi);
            TAPBODY(bh0, bl0, (t / 5) * 32 + (t % 5));
            LOADB(bh0, bl0, t2, cbi);
            TAPBODY(bh1, bl1, (t1 / 5) * 32 + (t1 % 5));
        }
        TAPBODY(bh0, bl0, 4 * 32 + 4);
    }

    #pragma unroll
    for (int mf = 0; mf < 4; ++mf) {
        int prow = p0 + wm * 64 + mf * 16 + g * 4;
        #pragma unroll
        for (int nf = 0; nf < 2; ++nf) {
            int oc = oc0 + nf * 16 + m_in;
            #pragma unroll
            for (int r = 0; r < 4; ++r) {
                int pos = prow + r;
                if (pos < NPOS)
                    hpart[(((size_t)(cs * 4 + b) * NPOS + pos) << 8) + oc] =
                        acc[mf][nf][r];
            }
        }
    }
#undef STAGE_LOAD
#undef STAGE_WRITE
#undef LOADB
#undef TAPBODY
}

// ---------------------------------------------------------------------------
// 3. reduce partials + bias + channel-LN + GELU + 1x1(256->16) + tanh + clip
__global__ __launch_bounds__(256) void k_lnoff(const float* __restrict__ hpart,
                                               const float* __restrict__ b1,
                                               const float* __restrict__ g,
                                               const float* __restrict__ bb,
                                               const float* __restrict__ w2,
                                               const float* __restrict__ b2,
                                               const float* __restrict__ ref,
                                               float* __restrict__ loc) {
    const int pos = blockIdx.x, b = blockIdx.y, c = threadIdx.x;
    float v = b1[c];
    #pragma unroll
    for (int cs = 0; cs < 4; ++cs)
        v += hpart[((size_t)((cs * 4 + b) * NPOS + pos)) * 256 + c];

    float s1 = v, s2 = v * v;
    #pragma unroll
    for (int m = 32; m >= 1; m >>= 1) {
        s1 += __shfl_xor(s1, m);
        s2 += __shfl_xor(s2, m);
    }
    __shared__ float r1[4], r2[4];
    const int wv = c >> 6, ln = c & 63;
    if (ln == 0) { r1[wv] = s1; r2[wv] = s2; }
    __syncthreads();
    s1 = r1[0] + r1[1] + r1[2] + r1[3];
    s2 = r2[0] + r2[1] + r2[2] + r2[3];
    const float mu  = s1 * (1.f / 256.f);
    const float var = s2 * (1.f / 256.f) - mu * mu;
    const float rstd = 1.f / sqrtf(var + 1e-5f);
    const float xn = (v - mu) * rstd * g[c] + bb[c];
    const float ge = 0.5f * xn * (1.f + erff(xn * 0.70710678118654752f));

    __shared__ float ro[4][16];
    for (int o = 0; o < 16; ++o) {
        float pv = ge * w2[o * 256 + c];
        #pragma unroll
        for (int m = 32; m >= 1; m >>= 1) pv += __shfl_xor(pv, m);
        if (ln == 0) ro[wv][o] = pv;
    }
    __syncthreads();
    if (c < 16) {
        float off = ro[0][c] + ro[1][c] + ro[2][c] + ro[3][c] + b2[c];
        float t = tanhf(off);
        int hd = c >> 1, comp = c & 1;
        size_t li = ((size_t)((b * 8 + hd) * NPOS + pos)) * 2 + comp;
        float l = ref[li] + t;
        loc[li] = fminf(1.f, fmaxf(-1.f, l));
    }
}

// ---------------------------------------------------------------------------
// 4. FUSED bilinear grid_sample + k/v 32->32 projections.
//    Each thread owns one (bh,pos): gathers 32 sampled channels into regs
//    (values bitwise-identical to the old samp buffer) and feeds them
//    straight into the k/v FMAs — no samp round-trip, no strided re-reads.
//    grid 392 x 64 (25,088 threads exact).
__global__ __launch_bounds__(64) void k_gskv(const float* __restrict__ x,
                                             const float* __restrict__ loc,
                                             const float* __restrict__ kw,
                                             const float* __restrict__ kb,
                                             const float* __restrict__ vw,
                                             const float* __restrict__ vb,
                                             ushort_t* __restrict__ ktb,
                                             ushort_t* __restrict__ vtb) {
    __shared__ __align__(16) float kl[1024], vl[1024];
    const int tid = threadIdx.x;
    for (int i = tid; i < 1024; i += 64) {
        int o = i >> 5, c = i & 31;
        kl[c * 32 + o] = kw[i];
        vl[c * 32 + o] = vw[i];
    }
    __syncthreads();

    int idx = blockIdx.x * 64 + tid;    // 25,088 exact
    int pos = idx % NPOS;
    int bh  = idx / NPOS;
    float gx = loc[(size_t)idx * 2 + 0];
    float gy = loc[(size_t)idx * 2 + 1];
    float ix = (gx + 1.f) * 28.f - 0.5f;
    float iy = (gy + 1.f) * 28.f - 0.5f;
    float x0f = floorf(ix), y0f = floorf(iy);
    int x0 = (int)x0f, y0 = (int)y0f;
    float wx = ix - x0f, wy = iy - y0f;

    int xs[2] = { x0, x0 + 1 };
    int ys[2] = { y0, y0 + 1 };
    float wxs[2] = { 1.f - wx, wx };
    float wys[2] = { 1.f - wy, wy };
    int   cidx[4];
    float cw[4];
    #pragma unroll
    for (int a = 0; a < 2; ++a)
        #pragma unroll
        for (int bb2 = 0; bb2 < 2; ++bb2) {
            int yy = ys[a], xx = xs[bb2];
            bool inb = (xx >= 0) && (xx < W_) && (yy >= 0) && (yy < H_);
            int yyc = min(max(yy, 0), H_ - 1), xxc = min(max(xx, 0), W_ - 1);
            cidx[a * 2 + bb2] = yyc * W_ + xxc;
            cw[a * 2 + bb2] = inb ? (wys[a] * wxs[bb2]) : 0.f;
        }

    const float* xb = x + (size_t)bh * DPH * NS;
    float ak[32] = {}, av[32] = {};
    for (int c = 0; c < DPH; ++c) {
        const float* xc = xb + (size_t)c * NS;
        float sv = cw[0] * xc[cidx[0]] + cw[1] * xc[cidx[1]]
                 + cw[2] * xc[cidx[2]] + cw[3] * xc[cidx[3]];
        #pragma unroll
        for (int og = 0; og < 8; ++og) {
            float4 k4 = *(const float4*)&kl[c * 32 + og * 4];
            float4 v4 = *(const float4*)&vl[c * 32 + og * 4];
            ak[og * 4 + 0] = fmaf(sv, k4.x, ak[og * 4 + 0]);
            ak[og * 4 + 1] = fmaf(sv, k4.y, ak[og * 4 + 1]);
            ak[og * 4 + 2] = fmaf(sv, k4.z, ak[og * 4 + 2]);
            ak[og * 4 + 3] = fmaf(sv, k4.w, ak[og * 4 + 3]);
            av[og * 4 + 0] = fmaf(sv, v4.x, av[og * 4 + 0]);
            av[og * 4 + 1] = fmaf(sv, v4.y, av[og * 4 + 1]);
            av[og * 4 + 2] = fmaf(sv, v4.z, av[og * 4 + 2]);
            av[og * 4 + 3] = fmaf(sv, v4.w, av[og * 4 + 3]);
        }
    }
    uint_t kp[16];
    #pragma unroll
    for (int o = 0; o < 16; ++o)
        kp[o] = (uint_t)bf16rne(ak[2 * o] + kb[2 * o])
              | ((uint_t)bf16rne(ak[2 * o + 1] + kb[2 * o + 1]) << 16);
    uint4* kdst = (uint4*)(ktb + (size_t)idx * 32);
    kdst[0] = make_uint4(kp[0], kp[1], kp[2], kp[3]);
    kdst[1] = make_uint4(kp[4], kp[5], kp[6], kp[7]);
    kdst[2] = make_uint4(kp[8], kp[9], kp[10], kp[11]);
    kdst[3] = make_uint4(kp[12], kp[13], kp[14], kp[15]);
    #pragma unroll
    for (int o = 0; o < 32; ++o)
        vtb[((size_t)bh * 32 + o) * NPOS + pos] = bf16rne(av[o] + vb[o]);
}

// ---------------------------------------------------------------------------
// 4b. qpe = (query + pos_emb) -> FRAGMENT-MAJOR packed-split u32
//     [b][sblk(196)][cblk(8)][lane(64)][8].
__global__ __launch_bounds__(256) void k_qpe(const float* __restrict__ q,
                                             const float* __restrict__ pe,
                                             uint_t* __restrict__ qpe) {
    const int st = blockIdx.x, b = blockIdx.y;
    const int s0 = st * 64;
    __shared__ uint_t T[64 * 129];
    const int l = threadIdx.x & 63, w = threadIdx.x >> 6;

    for (int half = 0; half < 2; ++half) {
        #pragma unroll 4
        for (int cc = 0; cc < 32; ++cc) {
            int c = half * 128 + w * 32 + cc;
            size_t gi = (size_t)(b * 256 + c) * NS + s0 + l;
            T[l * 129 + w * 32 + cc] = packsplit(q[gi] + pe[gi]);
        }
        __syncthreads();
        #pragma unroll
        for (int it = 0; it < 4; ++it) {
            int u2 = threadIdx.x + it * 256;     // 0..1023
            int sblk = u2 >> 8;                  // 0..3
            int cbl  = (u2 >> 6) & 3;            // local cblk 0..3
            int lane = u2 & 63;
            int n = lane & 15, g = lane >> 4;
            const uint_t* src = T + (sblk * 16 + n) * 129 + cbl * 32 + g * 8;
            uint_t* dst = qpe + ((((size_t)b * NSB + st * 4 + sblk) * 8
                                  + half * 4 + cbl) * 64 + lane) * 8;
            *(uint4*)dst       = make_uint4(src[0], src[1], src[2], src[3]);
            *(uint4*)(dst + 4) = make_uint4(src[4], src[5], src[6], src[7]);
        }
        __syncthreads();
    }
}

// ---------------------------------------------------------------------------
// 5. streaming MFMA 256x256 projection — fragment-major in/out.
//    MODE 0: out bf16 fm [b][sblk][cblk][lane][8] (+bias) -> attn Q
//    MODE 1: out f32 [b][256][3136] (+bias) -> d_out
template<int MODE>
__global__ __launch_bounds__(256) void k_proj(const uint_t* __restrict__ inT,
                                              const ushort_t* __restrict__ wh,
                                              const ushort_t* __restrict__ wl,
                                              const float* __restrict__ bias,
                                              float* __restrict__ outf,
                                              ushort_t* __restrict__ outb) {
    const int st = blockIdx.x, og = blockIdx.y, b = blockIdx.z;
    const int tid = threadIdx.x, lane = tid & 63, wid = tid >> 6;
    const int wsg = wid & 1, wo = wid >> 1;
    const int n = lane & 15, g = lane >> 4;
    const int s0 = st * 64 + wsg * 32;
    const int sb0 = s0 >> 4;
    const int oc0 = og * 64 + wo * 32;
    const int ocf0 = oc0 >> 4;

    f32x4 acc[2][2];
    #pragma unroll
    for (int i = 0; i < 2; ++i)
        #pragma unroll
        for (int j = 0; j < 2; ++j)
            acc[i][j] = (f32x4){0.f, 0.f, 0.f, 0.f};

    #pragma unroll 2
    for (int kf = 0; kf < 8; ++kf) {
        bf16x8 awh[2], awl[2];
        #pragma unroll
        for (int mf = 0; mf < 2; ++mf) {
            size_t a = (((size_t)(ocf0 + mf) * 8 + kf) * 64 + lane) * 8;
            awh[mf] = *(const bf16x8*)(wh + a);
            awl[mf] = *(const bf16x8*)(wl + a);
        }
        bf16x8 bh[2], bl[2];
        #pragma unroll
        for (int nf = 0; nf < 2; ++nf) {
            const uint_t* p = inT + ((((size_t)b * NSB + sb0 + nf) * 8 + kf) * 64 + lane) * 8;
            uint4 u = *(const uint4*)p, v = *(const uint4*)(p + 4);
            bh[nf] = mk8((u.x >> 16) | (u.y & 0xFFFF0000u),
                         (u.z >> 16) | (u.w & 0xFFFF0000u),
                         (v.x >> 16) | (v.y & 0xFFFF0000u),
                         (v.z >> 16) | (v.w & 0xFFFF0000u));
            bl[nf] = mk8((u.x & 0xFFFFu) | (u.y << 16),
                         (u.z & 0xFFFFu) | (u.w << 16),
                         (v.x & 0xFFFFu) | (v.y << 16),
                         (v.z & 0xFFFFu) | (v.w << 16));
        }
        #pragma unroll
        for (int mf = 0; mf < 2; ++mf)
            #pragma unroll
            for (int nf = 0; nf < 2; ++nf) {
                acc[mf][nf] = __builtin_amdgcn_mfma_f32_16x16x32_bf16(
                    awh[mf], bh[nf], acc[mf][nf], 0, 0, 0);
                acc[mf][nf] = __builtin_amdgcn_mfma_f32_16x16x32_bf16(
                    awh[mf], bl[nf], acc[mf][nf], 0, 0, 0);
                acc[mf][nf] = __builtin_amdgcn_mfma_f32_16x16x32_bf16(
                    awl[mf], bh[nf], acc[mf][nf], 0, 0, 0);
            }
    }

    #pragma unroll
    for (int mf = 0; mf < 2; ++mf) {
        const int ocr = oc0 + mf * 16 + g * 4;
        float bs[4];
        #pragma unroll
        for (int r = 0; r < 4; ++r) bs[r] = bias[ocr + r];
        #pragma unroll
        for (int nf = 0; nf < 2; ++nf) {
            if (MODE == 0) {
                const int cblk = oc0 >> 5;
                const int lane2 = (mf * 2 + (g >> 1)) * 16 + n;
                uint_t p0 = (uint_t)bf16rne(acc[mf][nf][0] + bs[0])
                          | ((uint_t)bf16rne(acc[mf][nf][1] + bs[1]) << 16);
                uint_t p1 = (uint_t)bf16rne(acc[mf][nf][2] + bs[2])
                          | ((uint_t)bf16rne(acc[mf][nf][3] + bs[3]) << 16);
                *(uint2*)(outb + (((size_t)b * NSB + sb0 + nf) * 8 + cblk) * 512
                          + lane2 * 8 + (g & 1) * 4) = make_uint2(p0, p1);
            } else {
                int sc = s0 + nf * 16 + n;
                #pragma unroll
                for (int r = 0; r < 4; ++r)
                    outf[(size_t)(b * 256 + ocr + r) * NS + sc] =
                        acc[mf][nf][r] + bs[r];
            }
        }
    }
}

// ---------------------------------------------------------------------------
// 7. MFMA flash attention. grid (25 qtile, 32 bh), 256 thr = 4 waves.
__global__ __launch_bounds__(256) void k_attn_mfma(const ushort_t* __restrict__ qbf,
                                                   const ushort_t* __restrict__ ktb,
                                                   const ushort_t* __restrict__ vtb,
                                                   uint_t* __restrict__ attnT) {
    const int qt = blockIdx.x, bh = blockIdx.y;
    const int b = bh >> 3, head = bh & 7;
    const int tid = threadIdx.x, lane = tid & 63, wid = tid >> 6;
    const int n = lane & 15, g = lane >> 4;

    __shared__ __align__(16) ushort_t sP[4][32 * 72];    // per-wave [q][kv], pad 72

    const int q0 = qt * 128 + wid * 32;

    bf16x8 qf[2];
    #pragma unroll
    for (int nf = 0; nf < 2; ++nf) {
        int sb = min(q0 / 16 + nf, NSB - 1);
        qf[nf] = *(const bf16x8*)(qbf + ((((size_t)b * NSB + sb) * 8 + head) * 64 + lane) * 8);
    }

    const ushort_t* kbase = ktb + (size_t)bh * NPOS * 32;
    const ushort_t* vbase = vtb + (size_t)bh * 32 * NPOS;
    ushort_t* myP = sP[wid];

    f32x4 o_acc[2][2];
    #pragma unroll
    for (int i = 0; i < 2; ++i)
        #pragma unroll
        for (int j = 0; j < 2; ++j)
            o_acc[i][j] = (f32x4){0.f, 0.f, 0.f, 0.f};
    float mrun[2] = {-1e30f, -1e30f};
    float lrun[2] = {0.f, 0.f};

    for (int t = 0; t < 12; ++t) {
        const int kvt = t * 64;
        bf16x8 kf[4];
        #pragma unroll
        for (int mf = 0; mf < 4; ++mf)
            kf[mf] = *(const bf16x8*)(kbase + (size_t)(kvt + mf * 16 + n) * 32 + g * 8);
        bf16x8 vf[2][2];
        #pragma unroll
        for (int mv = 0; mv < 2; ++mv)
            #pragma unroll
            for (int kc = 0; kc < 2; ++kc)
                vf[mv][kc] = *(const bf16x8*)(vbase + (size_t)(mv * 16 + n) * NPOS
                                              + kvt + kc * 32 + g * 8);

        f32x4 acc[4][2];
        #pragma unroll
        for (int mf = 0; mf < 4; ++mf)
            #pragma unroll
            for (int nf = 0; nf < 2; ++nf)
                acc[mf][nf] = __builtin_amdgcn_mfma_f32_16x16x32_bf16(
                    kf[mf], qf[nf], (f32x4){0.f, 0.f, 0.f, 0.f}, 0, 0, 0);

        #pragma unroll
        for (int nf = 0; nf < 2; ++nf) {
            float s[4][4];
            float tmax = -1e30f;
            #pragma unroll
            for (int mf = 0; mf < 4; ++mf)
                #pragma unroll
                for (int r = 0; r < 4; ++r) {
                    s[mf][r] = acc[mf][nf][r] * (1.f / 16.f);
                    tmax = fmaxf(tmax, s[mf][r]);
                }
            tmax = fmaxf(tmax, __shfl_xor(tmax, 16));
            tmax = fmaxf(tmax, __shfl_xor(tmax, 32));
            float mnew = fmaxf(mrun[nf], tmax);
            float corr = __expf(mrun[nf] - mnew);
            mrun[nf] = mnew;
            float psum = 0.f;
            float p[4][4];
            #pragma unroll
            for (int mf = 0; mf < 4; ++mf)
                #pragma unroll
                for (int r = 0; r < 4; ++r) {
                    p[mf][r] = __expf(s[mf][r] - mnew);
                    psum += p[mf][r];
                }
            psum += __shfl_xor(psum, 16);
            psum += __shfl_xor(psum, 32);
            lrun[nf] = lrun[nf] * corr + psum;
            #pragma unroll
            for (int mv = 0; mv < 2; ++mv)
                #pragma unroll
                for (int r = 0; r < 4; ++r)
                    o_acc[mv][nf][r] *= corr;
            #pragma unroll
            for (int mf = 0; mf < 4; ++mf) {
                uint_t lo = cvtpk_bf16(p[mf][0], p[mf][1]);
                uint_t hi = cvtpk_bf16(p[mf][2], p[mf][3]);
                *(uint2*)(myP + (nf * 16 + n) * 72 + mf * 16 + g * 4) =
                    make_uint2(lo, hi);
            }
        }

        #pragma unroll
        for (int kc = 0; kc < 2; ++kc)
            #pragma unroll
            for (int nf = 0; nf < 2; ++nf) {
                bf16x8 pb = *(const bf16x8*)(myP + (nf * 16 + n) * 72
                                             + kc * 32 + g * 8);
                #pragma unroll
                for (int mv = 0; mv < 2; ++mv)
                    o_acc[mv][nf] = __builtin_amdgcn_mfma_f32_16x16x32_bf16(
                        vf[mv][kc], pb, o_acc[mv][nf], 0, 0, 0);
            }
    }

    // epilog tile: kv 768..783
    {
        const int kvt = 768;
        bf16x8 kf0 = *(const bf16x8*)(kbase + (size_t)(kvt + n) * 32 + g * 8);
        bf16x8 vf[2];
        int kvo = kvt + g * 8; if (kvo > 776) kvo = 776;
        #pragma unroll
        for (int mv = 0; mv < 2; ++mv)
            vf[mv] = *(const bf16x8*)(vbase + (size_t)(mv * 16 + n) * NPOS + kvo);

        f32x4 acc0[2];
        #pragma unroll
        for (int nf = 0; nf < 2; ++nf)
            acc0[nf] = __builtin_amdgcn_mfma_f32_16x16x32_bf16(
                kf0, qf[nf], (f32x4){0.f, 0.f, 0.f, 0.f}, 0, 0, 0);

        #pragma unroll
        for (int nf = 0; nf < 2; ++nf) {
            float s[4], tmax = -1e30f;
            #pragma unroll
            for (int r = 0; r < 4; ++r) {
                s[r] = acc0[nf][r] * (1.f / 16.f);
                tmax = fmaxf(tmax, s[r]);
            }
            tmax = fmaxf(tmax, __shfl_xor(tmax, 16));
            tmax = fmaxf(tmax, __shfl_xor(tmax, 32));
            float mnew = fmaxf(mrun[nf], tmax);
            float corr = __expf(mrun[nf] - mnew);
            mrun[nf] = mnew;
            float psum = 0.f, p[4];
            #pragma unroll
            for (int r = 0; r < 4; ++r) { p[r] = __expf(s[r] - mnew); psum += p[r]; }
            psum += __shfl_xor(psum, 16);
            psum += __shfl_xor(psum, 32);
            lrun[nf] = lrun[nf] * corr + psum;
            #pragma unroll
            for (int mv = 0; mv < 2; ++mv)
                #pragma unroll
                for (int r = 0; r < 4; ++r)
                    o_acc[mv][nf][r] *= corr;
            uint_t lo = cvtpk_bf16(p[0], p[1]);
            uint_t hi = cvtpk_bf16(p[2], p[3]);
            *(uint2*)(myP + (nf * 16 + n) * 72 + g * 4) = make_uint2(lo, hi);
            *(uint2*)(myP + (nf * 16 + n) * 72 + 16 + g * 4) = make_uint2(0u, 0u);
        }
        #pragma unroll
        for (int nf = 0; nf < 2; ++nf) {
            bf16x8 pb = *(const bf16x8*)(myP + (nf * 16 + n) * 72 + g * 8);
            #pragma unroll
            for (int mv = 0; mv < 2; ++mv)
                o_acc[mv][nf] = __builtin_amdgcn_mfma_f32_16x16x32_bf16(
                    vf[mv], pb, o_acc[mv][nf], 0, 0, 0);
        }
    }

    // normalize + store attnT FRAGMENT-MAJOR packed-split u32
    #pragma unroll
    for (int nf = 0; nf < 2; ++nf) {
        if (q0 + nf * 16 < NS) {
            float inv = 1.f / lrun[nf];
            const size_t sbase = (((size_t)b * NSB + (q0 / 16 + nf)) * 8 + head) * 512;
            #pragma unroll
            for (int mv = 0; mv < 2; ++mv) {
                uint_t pk[4];
                #pragma unroll
                for (int r = 0; r < 4; ++r)
                    pk[r] = packsplit(o_acc[mv][nf][r] * inv);
                const int lane2 = (mv * 2 + (g >> 1)) * 16 + n;
                *(uint4*)(attnT + sbase + lane2 * 8 + (g & 1) * 4) =
                    make_uint4(pk[0], pk[1], pk[2], pk[3]);
            }
        }
    }
}

// ---------------------------------------------------------------------------
extern "C" void kernel_launch(void* const* d_in, const int* in_sizes, int n_in,
                              void* d_out, int out_size, void* d_ws, size_t ws_size,
                              hipStream_t stream) {
    const float* query = (const float*)d_in[0];
    const float* x     = (const float*)d_in[1];
    const float* refp  = (const float*)d_in[2];
    const float* pe    = (const float*)d_in[3];
    const float* w1    = (const float*)d_in[4];
    const float* b1    = (const float*)d_in[5];
    const float* lng   = (const float*)d_in[6];
    const float* lnb   = (const float*)d_in[7];
    const float* w2    = (const float*)d_in[8];
    const float* b2    = (const float*)d_in[9];
    const float* qw    = (const float*)d_in[10];
    const float* qb    = (const float*)d_in[11];
    const float* kw    = (const float*)d_in[12];
    const float* kb    = (const float*)d_in[13];
    const float* vw    = (const float*)d_in[14];
    const float* vb    = (const float*)d_in[15];
    const float* ow    = (const float*)d_in[16];
    const float* ob    = (const float*)d_in[17];

    float* ws  = (float*)d_ws;
    float* out = (float*)d_out;

    uint_t*   rec    = (uint_t*)(ws + OFF_REC);
    float*    hpart  = ws + OFF_HPART;
    float*    loc    = ws + OFF_LOC;
    ushort_t* ktb    = (ushort_t*)(ws + OFF_KTB);
    ushort_t* vtb    = (ushort_t*)(ws + OFF_VTB);
    ushort_t* w256   = (ushort_t*)(ws + OFF_W256);
    ushort_t* wrep_hi = (ushort_t*)(ws + OFF_WREPC);
    uint_t*   qpe    = (uint_t*)(ws + OFF_QPE);     // alias WREPC (dead after conv)
    ushort_t* qbf    = (ushort_t*)(ws + OFF_QBF);   // alias REC (dead after conv)
    uint_t*   attnT  = (uint_t*)(ws + OFF_ATTNT);   // alias HPART (dead after lnoff)

    ushort_t* qwh = w256;
    ushort_t* qwl = w256 + 65536;
    ushort_t* owh = w256 + 131072;
    ushort_t* owl = w256 + 196608;

    k_prep<<<7904, 256, 0, stream>>>(query, x, w1, qw, ow,
                                     rec, wrep_hi, wrep_hi + 3276800u, w256);
    k_conv_mfma<<<224, 512, 0, stream>>>(rec, wrep_hi, hpart);
    k_lnoff<<<dim3(784, 4), 256, 0, stream>>>(hpart, b1, lng, lnb, w2, b2, refp, loc);
    k_qpe<<<dim3(49, 4), 256, 0, stream>>>(query, pe, qpe);
    k_proj<0><<<dim3(49, 4, 4), 256, 0, stream>>>(qpe, qwh, qwl, qb, nullptr, qbf);
    k_gskv<<<392, 64, 0, stream>>>(x, loc, kw, kb, vw, vb, ktb, vtb);
    k_attn_mfma<<<dim3(25, 32), 256, 0, stream>>>(qbf, ktb, vtb, attnT);
    k_proj<1><<<dim3(49, 4, 4), 256, 0, stream>>>(attnT, owh, owl, ob, out, nullptr);
}